// Round 17
// baseline (2284955.859 us; speedup 1.0000x reference)
//
#include <hip/hip_runtime.h>

#define Bq 8
#define Tq 2048
#define Dq 512

typedef __attribute__((ext_vector_type(8))) _Float16 f16x8;  // 8 f16 = 4 VGPRs
typedef __attribute__((ext_vector_type(8))) short u16x8;
typedef __attribute__((ext_vector_type(4))) float f32x4;

// ---------------------------------------------------------------------------
// f32 -> (hi,lo) f16 split planes, x*256 pre-scale (undone by 2^-16 in GEMM).
// Used only for the (small, reused) weight matrices.
// ---------------------------------------------------------------------------
__global__ __launch_bounds__(256) void cvt_f16split(
    const float* __restrict__ s, ushort* __restrict__ hi,
    ushort* __restrict__ lo, int n8) {
  int i = blockIdx.x * 256 + threadIdx.x;
  if (i >= n8) return;
  const float4* sp = reinterpret_cast<const float4*>(s) + i * 2;
  float4 a = sp[0], b = sp[1];
  float x[8] = {a.x, a.y, a.z, a.w, b.x, b.y, b.z, b.w};
  ushort h[8], l[8];
#pragma unroll
  for (int e = 0; e < 8; e++) {
    float xs = x[e] * 256.0f;
    _Float16 hh = (_Float16)xs;
    _Float16 ll = (_Float16)(xs - (float)hh);
    h[e] = *(ushort*)&hh;
    l[e] = *(ushort*)&ll;
  }
  *reinterpret_cast<u16x8*>(hi + (size_t)i * 8) = *reinterpret_cast<u16x8*>(h);
  *reinterpret_cast<u16x8*>(lo + (size_t)i * 8) = *reinterpret_cast<u16x8*>(l);
}

// In-register split of 8 f32 into hi/lo f16 planes — same elementwise math as
// cvt_f16split (R16-verified bit-identical PRE, absmax 0.0078).
__device__ __forceinline__ void split8(const float4& a, const float4& b,
                                       f16x8& hi, f16x8& lo) {
  float x[8] = {a.x, a.y, a.z, a.w, b.x, b.y, b.z, b.w};
#pragma unroll
  for (int e = 0; e < 8; e++) {
    float xs = x[e] * 256.0f;
    _Float16 hh = (_Float16)xs;
    _Float16 ll = (_Float16)(xs - (float)hh);
    hi[e] = hh;
    lo[e] = ll;
  }
}

// ===========================================================================
// Common helpers.
// ===========================================================================
template <int CTRL>
__device__ __forceinline__ float dppadd(float v) {
  int r = __builtin_amdgcn_update_dpp(0, __float_as_int(v), CTRL, 0xF, 0xF, true);
  return v + __int_as_float(r);
}
__device__ __forceinline__ float wave_sum_bcast(float v) {
  v = dppadd<0x111>(v);
  v = dppadd<0x112>(v);
  v = dppadd<0x114>(v);
  v = dppadd<0x118>(v);
  v = dppadd<0x142>(v);
  v = dppadd<0x143>(v);
  return __int_as_float(__builtin_amdgcn_readlane(__float_as_int(v), 63));
}

// Bounded agent-scope wait on a monotone counter (bug -> absmax fail, not hang).
__device__ __forceinline__ void wait_band(int* done, int idx, int target) {
  int it = 0;
  while (__hip_atomic_load(&done[idx], __ATOMIC_ACQUIRE,
                           __HIP_MEMORY_SCOPE_AGENT) < target) {
    __builtin_amdgcn_s_sleep(8);
    if (++it > (1 << 22)) break;
  }
}

// ===========================================================================
// 4-wave cooperative scan step — R15/R16-verified (absmax 0.0078). NUMERICS
// ARE R5's EXACT ORDER. Do not re-derive (R14 lesson: ulp-level reordering
// diverges chaotically). Only non-FP addition vs R16: publish scan band
// progress to done[64+b] (relaxed, advisory — producers use it to throttle
// their lookahead so the scan's reads stay L3-resident).
// ===========================================================================
template <int S0, int S1, int S2, int S3, int S4, int SLOT, int SLW>
__device__ __forceinline__ void scan_step4(
    int t, float m3, float m4, int lane, int w, int dbase,
    const float* __restrict__ ob, const float* __restrict__ Gb,
    const float* __restrict__ Pgb, const float* __restrict__ pmb,
    float* __restrict__ po, float (*red)[5][4],
    int* done, int bb, int& bandReady,
    float2 (&ow)[8], float2 (&gw)[8], float2 (&pm)[8], float2 (&pg)[8],
    float2& st) {
  int rw = t + 5; if (rw > Tq - 1) rw = Tq - 1;
  int band = rw >> 7;
  if (band > bandReady) {  // once per 128 steps: gate on producer progress
    wait_band(done, bb + band, 6);
    bandReady = band;
  }
  __builtin_amdgcn_sched_barrier(0);
  ow[SLW] = *(const float2*)(ob  + (size_t)rw * Dq + dbase);
  gw[SLW] = *(const float2*)(Gb  + (size_t)rw * Dq + dbase);
  pm[SLW] = *(const float2*)(pmb + (size_t)rw * Dq + dbase);
  pg[SLW] = *(const float2*)(Pgb + (size_t)rw * Dq + dbase);
  __builtin_amdgcn_sched_barrier(0);

  // ---- partial scores over this wave's 128 dims (R5-exact) ----
  const float scale = 0.04419417382415922f;  // 1/sqrt(512)
  float s0 = st.x * ow[S0].x; s0 = fmaf(st.y, ow[S0].y, s0);
  float s1 = st.x * ow[S1].x; s1 = fmaf(st.y, ow[S1].y, s1);
  float s2 = st.x * ow[S2].x; s2 = fmaf(st.y, ow[S2].y, s2);
  float s3 = st.x * ow[S3].x; s3 = fmaf(st.y, ow[S3].y, s3);
  float s4 = st.x * ow[S4].x; s4 = fmaf(st.y, ow[S4].y, s4);
  s0 = wave_sum_bcast(s0);
  s1 = wave_sum_bcast(s1);
  s2 = wave_sum_bcast(s2);
  s3 = wave_sum_bcast(s3);
  s4 = wave_sum_bcast(s4);
  s0 *= scale; s1 *= scale; s2 *= scale;
  s3 *= scale * m3;  // masked scores -> exact 0
  s4 *= scale * m4;

  float pv = s0;
  pv = (lane == 1) ? s1 : pv;
  pv = (lane == 2) ? s2 : pv;
  pv = (lane == 3) ? s3 : pv;
  pv = (lane == 4) ? s4 : pv;
  if (lane < 5) red[t & 1][lane][w] = pv;

  asm volatile("s_waitcnt lgkmcnt(0)" ::: "memory");
  __builtin_amdgcn_sched_barrier(0);
  __builtin_amdgcn_s_barrier();   // raw: no compiler vmcnt(0) drain
  __builtin_amdgcn_sched_barrier(0);

  // ---- full scores + softmax (R5-exact) ----
  float fs[5];
#pragma unroll
  for (int j = 0; j < 5; j++) {
    float4 rv = *(const float4*)(&red[t & 1][j][0]);
    fs[j] = (rv.x + rv.y) + (rv.z + rv.w);
  }
  float mx = fmaxf(fmaxf(fmaxf(fs[0], fs[1]), fmaxf(fs[2], fs[3])), fs[4]);
  float e0 = __expf(fs[0] - mx), e1 = __expf(fs[1] - mx), e2 = __expf(fs[2] - mx);
  float e3 = __expf(fs[3] - mx), e4 = __expf(fs[4] - mx);
  float inv = __fdividef(1.0f, e0 + e1 + e2 + e3 + e4);
  float q0 = e0 * inv, q1 = e1 * inv, q2 = e2 * inv;
  float q3 = e3 * inv * m3, q4 = e4 * inv * m4;  // padded rows contribute 0

  // ---- weighted sums, gate, state update (R5-exact fma chains) ----
  float ax = q0 * ow[S0].x; ax = fmaf(q1, ow[S1].x, ax); ax = fmaf(q2, ow[S2].x, ax);
  ax = fmaf(q3, ow[S3].x, ax); ax = fmaf(q4, ow[S4].x, ax);
  float ay = q0 * ow[S0].y; ay = fmaf(q1, ow[S1].y, ay); ay = fmaf(q2, ow[S2].y, ay);
  ay = fmaf(q3, ow[S3].y, ay); ay = fmaf(q4, ow[S4].y, ay);
  float gx = q0 * gw[S0].x; gx = fmaf(q1, gw[S1].x, gx); gx = fmaf(q2, gw[S2].x, gx);
  gx = fmaf(q3, gw[S3].x, gx); gx = fmaf(q4, gw[S4].x, gx);
  float gy = q0 * gw[S0].y; gy = fmaf(q1, gw[S1].y, gy); gy = fmaf(q2, gw[S2].y, gy);
  gy = fmaf(q3, gw[S3].y, gy); gy = fmaf(q4, gw[S4].y, gy);

  float2 ot;
  ot.x = fmaf(ax, __fdividef(1.f, 1.f + __expf(-(pg[SLOT].x + gx))), pm[SLOT].x);
  ot.y = fmaf(ay, __fdividef(1.f, 1.f + __expf(-(pg[SLOT].y + gy))), pm[SLOT].y);
  st = ot;
  *(float2*)(po + (size_t)t * Dq + dbase) = ot;

  // advisory progress publish (non-FP; once per 128 steps)
  if (lane == 0 && w == 0 && (t & 127) == 127) {
    __hip_atomic_store(&done[64 + (bb >> 4)], t >> 7, __ATOMIC_RELAXED,
                       __HIP_MEMORY_SCOPE_AGENT);
  }
}

// ===========================================================================
// FUSED kernel: blocks 0..7 = per-batch 4-wave scans; blocks 8.. = paired
// GEMM producers (band-major; 48 blocks/band; each runs 2 same-mode by-roles
// back-to-back for A-reuse; publishes done[b*16+band], target 6). Producers
// of band k>2 throttle until min scan progress >= k-2 (advisory L3 window).
// ===========================================================================
__global__ __launch_bounds__(256, 1) void fused_kernel(
    const float* __restrict__ O,
    const ushort* __restrict__ Wmh, const ushort* __restrict__ Wml,
    const ushort* __restrict__ Wgh, const ushort* __restrict__ Wgl,
    const float* __restrict__ bm, const float* __restrict__ bg,
    float* __restrict__ Pg, float* __restrict__ Gm,
    float* __restrict__ out, int* __restrict__ done) {
  __shared__ __align__(16) float red[2][5][4];  // score partials (scan only)

  if (blockIdx.x < 8) {
    // ---------------- scan: 4 waves, wave w owns dims [128w,128w+128) ------
    int b = blockIdx.x;
    int tid = threadIdx.x;
    int w = tid >> 6;
    int lane = tid & 63;
    int dbase = w * 128 + lane * 2;
    int bb = b * 16;
    const float* ob  = O   + (size_t)b * Tq * Dq;
    const float* Gb  = Gm  + (size_t)b * Tq * Dq;
    const float* Pgb = Pg  + (size_t)b * Tq * Dq;
    const float* pmb = out + (size_t)b * Tq * Dq;  // PRE_mlp lives in d_out
    float* po = out + (size_t)b * Tq * Dq;

    int bandReady = -1;
    wait_band(done, bb + 0, 6);
    bandReady = 0;
    __builtin_amdgcn_sched_barrier(0);

    float2 ow[8], gw[8], pm[8], pg[8];
    float2 st = make_float2(0.f, 0.f);
#pragma unroll
    for (int r = 0; r < 5; r++) {
      ow[r] = *(const float2*)(ob  + (size_t)r * Dq + dbase);
      gw[r] = *(const float2*)(Gb  + (size_t)r * Dq + dbase);
      pm[r] = *(const float2*)(pmb + (size_t)r * Dq + dbase);
      pg[r] = *(const float2*)(Pgb + (size_t)r * Dq + dbase);
    }

#define SS(t_, m3_, m4_, A,B,C,D,E, SL_, LW_)                                  \
    scan_step4<A,B,C,D,E, SL_, LW_>(t_, m3_, m4_, lane, w, dbase, ob, Gb,      \
        Pgb, pmb, po, red, done, bb, bandReady, ow, gw, pm, pg, st)

    SS(0, 0.f, 0.f, 0,1,2,3,4, 0, 5);
    SS(1, 1.f, 0.f, 0,1,2,3,4, 1, 6);
    for (int tb = 2; tb <= 2034; tb += 8) {
      SS(tb+0, 1.f, 1.f, 0,1,2,3,4, 2, 7);
      SS(tb+1, 1.f, 1.f, 1,2,3,4,5, 3, 0);
      SS(tb+2, 1.f, 1.f, 2,3,4,5,6, 4, 1);
      SS(tb+3, 1.f, 1.f, 3,4,5,6,7, 5, 2);
      SS(tb+4, 1.f, 1.f, 4,5,6,7,0, 6, 3);
      SS(tb+5, 1.f, 1.f, 5,6,7,0,1, 7, 4);
      SS(tb+6, 1.f, 1.f, 6,7,0,1,2, 0, 5);
      SS(tb+7, 1.f, 1.f, 7,0,1,2,3, 1, 6);
    }
    SS(2042, 1.f, 1.f, 0,1,2,3,4, 2, 7);
    SS(2043, 1.f, 1.f, 1,2,3,4,5, 3, 0);
    SS(2044, 1.f, 1.f, 2,3,4,5,6, 4, 1);
    SS(2045, 1.f, 1.f, 3,4,5,6,7, 5, 2);
    SS(2046, 1.f, 0.f, 4,5,6,7,0, 6, 3);
    SS(2047, 0.f, 0.f, 5,6,7,0,1, 7, 4);
#undef SS
    return;
  }

  // ---------------- paired GEMM producer ------------------------------------
  int g = blockIdx.x - 8;
  int band = g / 48;
  int rem = g % 48;
  int bat = rem / 6;
  int pr = rem % 6;               // 0..3: mode0 by={2pr,2pr+1}; 4..5: mode1
  int bt0 = (bat * 16 + band) * 128;
  int gb = bat * Tq;
  int t0 = bt0 % Tq;

  int tid = threadIdx.x;
  int l = tid & 63, w = tid >> 6;
  int wm = w >> 1, wn = w & 1;
  int r16 = l & 15, kg = l >> 4;

  // Throttle: stay <=2 bands ahead of the slowest scan (advisory L3 window).
  if (band > 2) {
    if (tid == 0) {
      int it = 0;
      for (;;) {
        int smin = 0x7fffffff;
#pragma unroll
        for (int bi = 0; bi < 8; bi++) {
          int v = __hip_atomic_load(&done[64 + bi], __ATOMIC_RELAXED,
                                    __HIP_MEMORY_SCOPE_AGENT);
          smin = v < smin ? v : smin;
        }
        if (smin >= band - 2 || ++it > (1 << 20)) break;
        __builtin_amdgcn_s_sleep(8);
      }
    }
    __syncthreads();
  }

  const f16x8 zz = {0, 0, 0, 0, 0, 0, 0, 0};

  if (pr >= 4) {
    // ---- MODE 1 pair: G = O @ Wg[:, 2560:]^T, by = 2(pr-4)+sub ----
#pragma unroll
    for (int sub = 0; sub < 2; sub++) {
      int by = 2 * (pr - 4) + sub;
      f32x4 acc[4][4] = {};
      const ushort *bph[4], *bpl[4];
      int ncol[4];
#pragma unroll
      for (int ni = 0; ni < 4; ni++) {
        int n_g = by * 128 + wn * 64 + ni * 16 + r16;
        ncol[ni] = n_g;
        size_t off = (size_t)n_g * 3072 + 2560 + kg * 8;
        bph[ni] = Wgh + off; bpl[ni] = Wgl + off;
      }
      const float* ap[4];
#pragma unroll
      for (int mi = 0; mi < 4; mi++) {
        ap[mi] = O + (size_t)(bt0 + wm * 64 + mi * 16 + r16) * Dq + kg * 8;
      }
#pragma unroll 4
      for (int ks = 0; ks < 16; ks++) {
        f16x8 Ah[4], Al[4], Bh[4], Bl[4];
#pragma unroll
        for (int mi = 0; mi < 4; mi++) {
          float4 v0 = *(const float4*)ap[mi];
          float4 v1 = *(const float4*)(ap[mi] + 4);
          ap[mi] += 32;
          split8(v0, v1, Ah[mi], Al[mi]);
        }
#pragma unroll
        for (int ni = 0; ni < 4; ni++) {
          Bh[ni] = *(const f16x8*)bph[ni]; bph[ni] += 32;
          Bl[ni] = *(const f16x8*)bpl[ni]; bpl[ni] += 32;
        }
#pragma unroll
        for (int mi = 0; mi < 4; mi++)
#pragma unroll
          for (int ni = 0; ni < 4; ni++) {
            acc[mi][ni] = __builtin_amdgcn_mfma_f32_16x16x32_f16(Ah[mi], Bh[ni], acc[mi][ni], 0, 0, 0);
            acc[mi][ni] = __builtin_amdgcn_mfma_f32_16x16x32_f16(Al[mi], Bh[ni], acc[mi][ni], 0, 0, 0);
            acc[mi][ni] = __builtin_amdgcn_mfma_f32_16x16x32_f16(Ah[mi], Bl[ni], acc[mi][ni], 0, 0, 0);
          }
      }
      const float SC = 1.0f / 65536.0f;
#pragma unroll
      for (int ni = 0; ni < 4; ni++) {
#pragma unroll
        for (int mi = 0; mi < 4; mi++) {
          int rowb = bt0 + wm * 64 + mi * 16 + kg * 4;
#pragma unroll
          for (int rr = 0; rr < 4; rr++)
            Gm[(size_t)(rowb + rr) * Dq + ncol[ni]] = acc[mi][ni][rr] * SC;
        }
      }
    }
  } else {
    // ---- MODE 0 pair: PRE, by = 2pr+sub (pairs never straddle Pm/Pg) ----
    int arow[4][5];
    uint vmask[4];
#pragma unroll
    for (int mi = 0; mi < 4; mi++) {
      int t = t0 + wm * 64 + mi * 16 + r16;
      int sh = 2 - t; if (sh < 0) sh = 0;
      int hi2 = t + 2; if (hi2 > Tq - 1) hi2 = Tq - 1;
      int lo2 = t - 2; if (lo2 < 0) lo2 = 0;
      int nv = hi2 - lo2 + 1;
      uint vm = 0;
#pragma unroll
      for (int j = 0; j < 5; j++) {
        int r = t - 2 + j + sh;
        if (r > Tq - 1) r = Tq - 1;
        arow[mi][j] = gb + r;
        if (j < nv) vm |= (1u << j);
      }
      vmask[mi] = vm;
    }
#pragma unroll
    for (int sub = 0; sub < 2; sub++) {
      int by = 2 * pr + sub;
      f32x4 acc[4][4] = {};
      const ushort *bph[4], *bpl[4];
      int ncol[4];
#pragma unroll
      for (int ni = 0; ni < 4; ni++) {
        int n_g = by * 128 + wn * 64 + ni * 16 + r16;
        ncol[ni] = n_g;
        size_t off;
        if (by < 4) { off = (size_t)n_g * 2560 + kg * 8; bph[ni] = Wmh + off; bpl[ni] = Wml + off; }
        else { off = (size_t)(n_g - 512) * 3072 + kg * 8; bph[ni] = Wgh + off; bpl[ni] = Wgl + off; }
      }
#pragma unroll
      for (int j = 0; j < 5; j++) {
        const float* ap[4];
        bool v[4];
#pragma unroll
        for (int mi = 0; mi < 4; mi++) {
          ap[mi] = O + (size_t)arow[mi][j] * Dq + kg * 8;
          v[mi] = (vmask[mi] >> j) & 1u;
        }
#pragma unroll 4
        for (int ks = 0; ks < 16; ks++) {
          f16x8 Ah[4], Al[4], Bh[4], Bl[4];
#pragma unroll
          for (int mi = 0; mi < 4; mi++) {
            float4 v0 = *(const float4*)ap[mi];
            float4 v1 = *(const float4*)(ap[mi] + 4);
            ap[mi] += 32;
            f16x8 th, tl;
            split8(v0, v1, th, tl);
            Ah[mi] = v[mi] ? th : zz;
            Al[mi] = v[mi] ? tl : zz;
          }
#pragma unroll
          for (int ni = 0; ni < 4; ni++) {
            Bh[ni] = *(const f16x8*)bph[ni]; bph[ni] += 32;
            Bl[ni] = *(const f16x8*)bpl[ni]; bpl[ni] += 32;
          }
#pragma unroll
          for (int mi = 0; mi < 4; mi++)
#pragma unroll
            for (int ni = 0; ni < 4; ni++) {
              acc[mi][ni] = __builtin_amdgcn_mfma_f32_16x16x32_f16(Ah[mi], Bh[ni], acc[mi][ni], 0, 0, 0);
              acc[mi][ni] = __builtin_amdgcn_mfma_f32_16x16x32_f16(Al[mi], Bh[ni], acc[mi][ni], 0, 0, 0);
              acc[mi][ni] = __builtin_amdgcn_mfma_f32_16x16x32_f16(Ah[mi], Bl[ni], acc[mi][ni], 0, 0, 0);
            }
        }
      }
      const float SC = 1.0f / 65536.0f;
      float* dst = (by < 4) ? out : Pg;  // PRE_mlp -> d_out, PRE_gate -> ws
      const float* bias = (by < 4) ? bm : bg;
#pragma unroll
      for (int ni = 0; ni < 4; ni++) {
        int oc = (by < 4) ? ncol[ni] : ncol[ni] - 512;
        float bi = bias[oc];
#pragma unroll
        for (int mi = 0; mi < 4; mi++) {
          int rowb = bt0 + wm * 64 + mi * 16 + kg * 4;
#pragma unroll
          for (int rr = 0; rr < 4; rr++)
            dst[(size_t)(rowb + rr) * Dq + oc] = fmaf(acc[mi][ni][rr], SC, bi);
        }
      }
    }
  }

  // ---- publish: all stores visible, then bump the band counter ----
  __threadfence();
  __syncthreads();
  if (tid == 0) {
    __hip_atomic_fetch_add(&done[bat * 16 + band], 1, __ATOMIC_RELEASE,
                           __HIP_MEMORY_SCOPE_AGENT);
  }
}

// ---------------------------------------------------------------------------
// f32 fallback (ws too small) — R1-verified serial GEMM + 4-wave scan.
// ---------------------------------------------------------------------------
__global__ __launch_bounds__(256) void gemm_pre(
    const float* __restrict__ O, const float* __restrict__ Wm,
    const float* __restrict__ Wg, const float* __restrict__ bm,
    const float* __restrict__ bg, float* __restrict__ Pm,
    float* __restrict__ Pg, float* __restrict__ Gm, int mode) {
  const int BM = 128, BN = 128, BK = 16;
  __shared__ float As[BK][132];
  __shared__ float Bs[BK][132];
  int tidx = threadIdx.x;
  int bt0 = blockIdx.x * BM;
  int b = bt0 / Tq;
  int t0 = bt0 % Tq;
  int n0 = blockIdx.y * BN;
  int K = mode ? Dq : 5 * Dq;
  int tx = tidx % 16, ty = tidx / 16, lr = tidx >> 2, lc = (tidx & 3) * 4;
  float acc[8][8];
#pragma unroll
  for (int i = 0; i < 8; i++)
#pragma unroll
    for (int j = 0; j < 8; j++) acc[i][j] = 0.f;
  for (int kb = 0; kb < K; kb += BK) {
#pragma unroll
    for (int h = 0; h < 2; h++) {
      int m = lr + h * 64;
      int t = t0 + m;
      float4 av;
      if (mode == 0) {
        int j = kb >> 9;
        int kcol = (kb & 511) + lc;
        int sh = 2 - t; if (sh < 0) sh = 0;
        int r = t - 2 + j + sh;
        int hi = t + 2; if (hi > Tq - 1) hi = Tq - 1;
        int lo2 = t - 2; if (lo2 < 0) lo2 = 0;
        int nv = hi - lo2 + 1;
        if (j < nv) av = *reinterpret_cast<const float4*>(O + ((size_t)b * Tq + r) * Dq + kcol);
        else av = make_float4(0.f, 0.f, 0.f, 0.f);
      } else {
        av = *reinterpret_cast<const float4*>(O + ((size_t)b * Tq + t) * Dq + kb + lc);
      }
      As[lc + 0][m] = av.x; As[lc + 1][m] = av.y;
      As[lc + 2][m] = av.z; As[lc + 3][m] = av.w;
    }
#pragma unroll
    for (int h = 0; h < 2; h++) {
      int n = lr + h * 64;
      int gn = n0 + n;
      const float* wrow;
      int col;
      if (mode == 0) {
        if (gn < 512) { wrow = Wm + (size_t)gn * 2560; col = kb + lc; }
        else          { wrow = Wg + (size_t)(gn - 512) * 3072; col = kb + lc; }
      } else {
        wrow = Wg + (size_t)gn * 3072; col = 2560 + kb + lc;
      }
      float4 bv = *reinterpret_cast<const float4*>(wrow + col);
      Bs[lc + 0][n] = bv.x; Bs[lc + 1][n] = bv.y;
      Bs[lc + 2][n] = bv.z; Bs[lc + 3][n] = bv.w;
    }
    __syncthreads();
#pragma unroll
    for (int kk = 0; kk < BK; kk++) {
      float a[8], bb[8];
      float4 a0 = *reinterpret_cast<float4*>(&As[kk][ty * 8]);
      float4 a1 = *reinterpret_cast<float4*>(&As[kk][ty * 8 + 4]);
      float4 b0 = *reinterpret_cast<float4*>(&Bs[kk][tx * 8]);
      float4 b1 = *reinterpret_cast<float4*>(&Bs[kk][tx * 8 + 4]);
      a[0]=a0.x; a[1]=a0.y; a[2]=a0.z; a[3]=a0.w; a[4]=a1.x; a[5]=a1.y; a[6]=a1.z; a[7]=a1.w;
      bb[0]=b0.x; bb[1]=b0.y; bb[2]=b0.z; bb[3]=b0.w; bb[4]=b1.x; bb[5]=b1.y; bb[6]=b1.z; bb[7]=b1.w;
#pragma unroll
      for (int i = 0; i < 8; i++)
#pragma unroll
        for (int j = 0; j < 8; j++) acc[i][j] = fmaf(a[i], bb[j], acc[i][j]);
    }
    __syncthreads();
  }
  int gn = n0 + tx * 8;
  float bias[8];
  float* dstbase;
  int coloff;
  if (mode == 0) {
    if (gn < 512) {
#pragma unroll
      for (int j = 0; j < 8; j++) bias[j] = bm[gn + j];
      dstbase = Pm; coloff = gn;
    } else {
#pragma unroll
      for (int j = 0; j < 8; j++) bias[j] = bg[gn - 512 + j];
      dstbase = Pg; coloff = gn - 512;
    }
  } else {
#pragma unroll
    for (int j = 0; j < 8; j++) bias[j] = 0.f;
    dstbase = Gm; coloff = gn;
  }
#pragma unroll
  for (int i = 0; i < 8; i++) {
    int bt = bt0 + ty * 8 + i;
    float4 v0 = make_float4(acc[i][0] + bias[0], acc[i][1] + bias[1],
                            acc[i][2] + bias[2], acc[i][3] + bias[3]);
    float4 v1 = make_float4(acc[i][4] + bias[4], acc[i][5] + bias[5],
                            acc[i][6] + bias[6], acc[i][7] + bias[7]);
    float4* d = reinterpret_cast<float4*>(dstbase + (size_t)bt * Dq + coloff);
    d[0] = v0;
    d[1] = v1;
  }
}

// Fallback serial 4-wave scan (done[] pre-filled >= 6 so gates are no-ops).
__global__ __launch_bounds__(256, 1) void scan_only(
    const float* __restrict__ O, const float* __restrict__ Gm,
    const float* __restrict__ Pg, const float* __restrict__ Pm,
    float* __restrict__ out, int* __restrict__ done) {
  __shared__ __align__(16) float red[2][5][4];
  int b = blockIdx.x;
  int tid = threadIdx.x;
  int w = tid >> 6;
  int lane = tid & 63;
  int dbase = w * 128 + lane * 2;
  int bb = b * 16;
  const float* ob  = O  + (size_t)b * Tq * Dq;
  const float* Gb  = Gm + (size_t)b * Tq * Dq;
  const float* Pgb = Pg + (size_t)b * Tq * Dq;
  const float* pmb = Pm + (size_t)b * Tq * Dq;
  float* po = out + (size_t)b * Tq * Dq;
  int bandReady = 15;

  float2 ow[8], gw[8], pm[8], pg[8];
  float2 st = make_float2(0.f, 0.f);
#pragma unroll
  for (int r = 0; r < 5; r++) {
    ow[r] = *(const float2*)(ob  + (size_t)r * Dq + dbase);
    gw[r] = *(const float2*)(Gb  + (size_t)r * Dq + dbase);
    pm[r] = *(const float2*)(pmb + (size_t)r * Dq + dbase);
    pg[r] = *(const float2*)(Pgb + (size_t)r * Dq + dbase);
  }
#define SS(t_, m3_, m4_, A,B,C,D,E, SL_, LW_)                                  \
  scan_step4<A,B,C,D,E, SL_, LW_>(t_, m3_, m4_, lane, w, dbase, ob, Gb,        \
      Pgb, pmb, po, red, done, bb, bandReady, ow, gw, pm, pg, st)
  SS(0, 0.f, 0.f, 0,1,2,3,4, 0, 5);
  SS(1, 1.f, 0.f, 0,1,2,3,4, 1, 6);
  for (int tb = 2; tb <= 2034; tb += 8) {
    SS(tb+0, 1.f, 1.f, 0,1,2,3,4, 2, 7);
    SS(tb+1, 1.f, 1.f, 1,2,3,4,5, 3, 0);
    SS(tb+2, 1.f, 1.f, 2,3,4,5,6, 4, 1);
    SS(tb+3, 1.f, 1.f, 3,4,5,6,7, 5, 2);
    SS(tb+4, 1.f, 1.f, 4,5,6,7,0, 6, 3);
    SS(tb+5, 1.f, 1.f, 5,6,7,0,1, 7, 4);
    SS(tb+6, 1.f, 1.f, 6,7,0,1,2, 0, 5);
    SS(tb+7, 1.f, 1.f, 7,0,1,2,3, 1, 6);
  }
  SS(2042, 1.f, 1.f, 0,1,2,3,4, 2, 7);
  SS(2043, 1.f, 1.f, 1,2,3,4,5, 3, 0);
  SS(2044, 1.f, 1.f, 2,3,4,5,6, 4, 1);
  SS(2045, 1.f, 1.f, 3,4,5,6,7, 5, 2);
  SS(2046, 1.f, 0.f, 4,5,6,7,0, 6, 3);
  SS(2047, 0.f, 0.f, 5,6,7,0,1, 7, 4);
#undef SS
}

extern "C" void kernel_launch(void* const* d_in, const int* in_sizes, int n_in,
                              void* d_out, int out_size, void* d_ws, size_t ws_size,
                              hipStream_t stream) {
  const float* O  = (const float*)d_in[0];
  const float* Wm = (const float*)d_in[1];
  const float* bm = (const float*)d_in[2];
  const float* Wg = (const float*)d_in[3];
  const float* bg = (const float*)d_in[4];
  float* out = (float*)d_out;

  const size_t NTOT = (size_t)Bq * Tq * Dq;   // 8.39M
  const size_t NWM = 512 * 2560, NWG = 512 * 3072;
  float* Pg = (float*)d_ws;
  float* Gm = Pg + NTOT;
  ushort* WMH = (ushort*)(Gm + NTOT);
  ushort* WML = WMH + NWM;
  ushort* WGH = WML + NWM;
  ushort* WGL = WGH + NWG;
  int* done = (int*)(WGL + NWG);              // 128 ints (0..63 bands, 64..71 sprog)

  size_t need = 2 * NTOT * 4 + 2 * (NWM + NWG) * 2 + 128 * 4;  // ~78.5 MB
  if (ws_size >= need) {
    hipMemsetAsync(done, 0, 128 * 4, stream);
    cvt_f16split<<<dim3((NWM / 8 + 255) / 256), dim3(256), 0, stream>>>(Wm, WMH, WML, NWM / 8);
    cvt_f16split<<<dim3((NWG / 8 + 255) / 256), dim3(256), 0, stream>>>(Wg, WGH, WGL, NWG / 8);
    fused_kernel<<<dim3(8 + 16 * 48), dim3(256), 0, stream>>>(
        O, WMH, WML, WGH, WGL, bm, bg, Pg, Gm, out, done);
  } else {
    bool sep = ws_size >= (size_t)(3 * NTOT * 4 + 128 * 4);
    float* Pm = sep ? (Gm + NTOT) : out;
    int* done2 = sep ? (int*)(Pm + NTOT) : (int*)(Gm + NTOT);
    hipMemsetAsync(done2, 6, 128 * 4, stream);  // every byte 6 -> >= 6
    gemm_pre<<<dim3(128, 8), dim3(256), 0, stream>>>(O, Wm, Wg, bm, bg, Pm, Pg, Gm, 0);
    gemm_pre<<<dim3(128, 4), dim3(256), 0, stream>>>(O, Wm, Wg, bm, bg, Pm, Pg, Gm, 1);
    scan_only<<<dim3(Bq), dim3(256), 0, stream>>>(O, Gm, Pg, Pm, out, done2);
  }
}

// Round 18
// 6075.462 us; speedup vs baseline: 376.0958x; 376.0958x over previous
//
#include <hip/hip_runtime.h>

#define Bq 8
#define Tq 2048
#define Dq 512

typedef __attribute__((ext_vector_type(8))) _Float16 f16x8;  // 8 f16 = 4 VGPRs
typedef __attribute__((ext_vector_type(8))) short u16x8;
typedef __attribute__((ext_vector_type(4))) float f32x4;

// ---------------------------------------------------------------------------
// f32 -> (hi,lo) f16 split planes, x*256 pre-scale (undone by 2^-16 in GEMM).
// Used only for the (small, reused) weight matrices.
// ---------------------------------------------------------------------------
__global__ __launch_bounds__(256) void cvt_f16split(
    const float* __restrict__ s, ushort* __restrict__ hi,
    ushort* __restrict__ lo, int n8) {
  int i = blockIdx.x * 256 + threadIdx.x;
  if (i >= n8) return;
  const float4* sp = reinterpret_cast<const float4*>(s) + i * 2;
  float4 a = sp[0], b = sp[1];
  float x[8] = {a.x, a.y, a.z, a.w, b.x, b.y, b.z, b.w};
  ushort h[8], l[8];
#pragma unroll
  for (int e = 0; e < 8; e++) {
    float xs = x[e] * 256.0f;
    _Float16 hh = (_Float16)xs;
    _Float16 ll = (_Float16)(xs - (float)hh);
    h[e] = *(ushort*)&hh;
    l[e] = *(ushort*)&ll;
  }
  *reinterpret_cast<u16x8*>(hi + (size_t)i * 8) = *reinterpret_cast<u16x8*>(h);
  *reinterpret_cast<u16x8*>(lo + (size_t)i * 8) = *reinterpret_cast<u16x8*>(l);
}

// In-register split of 8 f32 into hi/lo f16 planes — same elementwise math as
// cvt_f16split (R16-verified bit-identical PRE, absmax 0.0078).
__device__ __forceinline__ void split8(const float4& a, const float4& b,
                                       f16x8& hi, f16x8& lo) {
  float x[8] = {a.x, a.y, a.z, a.w, b.x, b.y, b.z, b.w};
#pragma unroll
  for (int e = 0; e < 8; e++) {
    float xs = x[e] * 256.0f;
    _Float16 hh = (_Float16)xs;
    _Float16 ll = (_Float16)(xs - (float)hh);
    hi[e] = hh;
    lo[e] = ll;
  }
}

// ===========================================================================
// Common helpers.
// ===========================================================================
template <int CTRL>
__device__ __forceinline__ float dppadd(float v) {
  int r = __builtin_amdgcn_update_dpp(0, __float_as_int(v), CTRL, 0xF, 0xF, true);
  return v + __int_as_float(r);
}
__device__ __forceinline__ float wave_sum_bcast(float v) {
  v = dppadd<0x111>(v);
  v = dppadd<0x112>(v);
  v = dppadd<0x114>(v);
  v = dppadd<0x118>(v);
  v = dppadd<0x142>(v);
  v = dppadd<0x143>(v);
  return __int_as_float(__builtin_amdgcn_readlane(__float_as_int(v), 63));
}

// Bounded agent-scope wait on a monotone counter (bug -> absmax fail, not hang).
__device__ __forceinline__ void wait_band(int* done, int idx, int target) {
  int it = 0;
  while (__hip_atomic_load(&done[idx], __ATOMIC_ACQUIRE,
                           __HIP_MEMORY_SCOPE_AGENT) < target) {
    __builtin_amdgcn_s_sleep(8);
    if (++it > (1 << 22)) break;
  }
}

// done[] layout: [0..127] producer band counters (bat*16+band);
//                [128..135] scan progress sprog[b] (R17 BUG: these lived at
//                64..71, colliding with batch-4 counters -> 2.28s of timeout
//                spins. Now disjoint.)
#define SPROG_BASE 128

// ===========================================================================
// 4-wave cooperative scan step — R15/R16-verified (absmax 0.0078). NUMERICS
// ARE R5's EXACT ORDER. Do not re-derive (R14 lesson). Non-FP only: publish
// scan band progress to done[SPROG_BASE+b] (relaxed, advisory throttle).
// ===========================================================================
template <int S0, int S1, int S2, int S3, int S4, int SLOT, int SLW>
__device__ __forceinline__ void scan_step4(
    int t, float m3, float m4, int lane, int w, int dbase,
    const float* __restrict__ ob, const float* __restrict__ Gb,
    const float* __restrict__ Pgb, const float* __restrict__ pmb,
    float* __restrict__ po, float (*red)[5][4],
    int* done, int bb, int& bandReady,
    float2 (&ow)[8], float2 (&gw)[8], float2 (&pm)[8], float2 (&pg)[8],
    float2& st) {
  int rw = t + 5; if (rw > Tq - 1) rw = Tq - 1;
  int band = rw >> 7;
  if (band > bandReady) {  // once per 128 steps: gate on producer progress
    wait_band(done, bb + band, 6);
    bandReady = band;
  }
  __builtin_amdgcn_sched_barrier(0);
  ow[SLW] = *(const float2*)(ob  + (size_t)rw * Dq + dbase);
  gw[SLW] = *(const float2*)(Gb  + (size_t)rw * Dq + dbase);
  pm[SLW] = *(const float2*)(pmb + (size_t)rw * Dq + dbase);
  pg[SLW] = *(const float2*)(Pgb + (size_t)rw * Dq + dbase);
  __builtin_amdgcn_sched_barrier(0);

  // ---- partial scores over this wave's 128 dims (R5-exact) ----
  const float scale = 0.04419417382415922f;  // 1/sqrt(512)
  float s0 = st.x * ow[S0].x; s0 = fmaf(st.y, ow[S0].y, s0);
  float s1 = st.x * ow[S1].x; s1 = fmaf(st.y, ow[S1].y, s1);
  float s2 = st.x * ow[S2].x; s2 = fmaf(st.y, ow[S2].y, s2);
  float s3 = st.x * ow[S3].x; s3 = fmaf(st.y, ow[S3].y, s3);
  float s4 = st.x * ow[S4].x; s4 = fmaf(st.y, ow[S4].y, s4);
  s0 = wave_sum_bcast(s0);
  s1 = wave_sum_bcast(s1);
  s2 = wave_sum_bcast(s2);
  s3 = wave_sum_bcast(s3);
  s4 = wave_sum_bcast(s4);
  s0 *= scale; s1 *= scale; s2 *= scale;
  s3 *= scale * m3;  // masked scores -> exact 0
  s4 *= scale * m4;

  float pv = s0;
  pv = (lane == 1) ? s1 : pv;
  pv = (lane == 2) ? s2 : pv;
  pv = (lane == 3) ? s3 : pv;
  pv = (lane == 4) ? s4 : pv;
  if (lane < 5) red[t & 1][lane][w] = pv;

  asm volatile("s_waitcnt lgkmcnt(0)" ::: "memory");
  __builtin_amdgcn_sched_barrier(0);
  __builtin_amdgcn_s_barrier();   // raw: no compiler vmcnt(0) drain
  __builtin_amdgcn_sched_barrier(0);

  // ---- full scores + softmax (R5-exact) ----
  float fs[5];
#pragma unroll
  for (int j = 0; j < 5; j++) {
    float4 rv = *(const float4*)(&red[t & 1][j][0]);
    fs[j] = (rv.x + rv.y) + (rv.z + rv.w);
  }
  float mx = fmaxf(fmaxf(fmaxf(fs[0], fs[1]), fmaxf(fs[2], fs[3])), fs[4]);
  float e0 = __expf(fs[0] - mx), e1 = __expf(fs[1] - mx), e2 = __expf(fs[2] - mx);
  float e3 = __expf(fs[3] - mx), e4 = __expf(fs[4] - mx);
  float inv = __fdividef(1.0f, e0 + e1 + e2 + e3 + e4);
  float q0 = e0 * inv, q1 = e1 * inv, q2 = e2 * inv;
  float q3 = e3 * inv * m3, q4 = e4 * inv * m4;  // padded rows contribute 0

  // ---- weighted sums, gate, state update (R5-exact fma chains) ----
  float ax = q0 * ow[S0].x; ax = fmaf(q1, ow[S1].x, ax); ax = fmaf(q2, ow[S2].x, ax);
  ax = fmaf(q3, ow[S3].x, ax); ax = fmaf(q4, ow[S4].x, ax);
  float ay = q0 * ow[S0].y; ay = fmaf(q1, ow[S1].y, ay); ay = fmaf(q2, ow[S2].y, ay);
  ay = fmaf(q3, ow[S3].y, ay); ay = fmaf(q4, ow[S4].y, ay);
  float gx = q0 * gw[S0].x; gx = fmaf(q1, gw[S1].x, gx); gx = fmaf(q2, gw[S2].x, gx);
  gx = fmaf(q3, gw[S3].x, gx); gx = fmaf(q4, gw[S4].x, gx);
  float gy = q0 * gw[S0].y; gy = fmaf(q1, gw[S1].y, gy); gy = fmaf(q2, gw[S2].y, gy);
  gy = fmaf(q3, gw[S3].y, gy); gy = fmaf(q4, gw[S4].y, gy);

  float2 ot;
  ot.x = fmaf(ax, __fdividef(1.f, 1.f + __expf(-(pg[SLOT].x + gx))), pm[SLOT].x);
  ot.y = fmaf(ay, __fdividef(1.f, 1.f + __expf(-(pg[SLOT].y + gy))), pm[SLOT].y);
  st = ot;
  *(float2*)(po + (size_t)t * Dq + dbase) = ot;

  // advisory progress publish (non-FP; once per 128 steps; DISJOINT slot)
  if (lane == 0 && w == 0 && (t & 127) == 127) {
    __hip_atomic_store(&done[SPROG_BASE + (bb >> 4)], t >> 7, __ATOMIC_RELAXED,
                       __HIP_MEMORY_SCOPE_AGENT);
  }
}

// ===========================================================================
// FUSED kernel: blocks 0..7 = per-batch 4-wave scans; blocks 8.. = paired
// GEMM producers (band-major; 48 blocks/band; 2 same-mode by-roles each;
// done[b*16+band] target 6). Band-k>2 producers throttle until min scan
// progress >= k-2 (advisory L3 window).
// ===========================================================================
__global__ __launch_bounds__(256, 1) void fused_kernel(
    const float* __restrict__ O,
    const ushort* __restrict__ Wmh, const ushort* __restrict__ Wml,
    const ushort* __restrict__ Wgh, const ushort* __restrict__ Wgl,
    const float* __restrict__ bm, const float* __restrict__ bg,
    float* __restrict__ Pg, float* __restrict__ Gm,
    float* __restrict__ out, int* __restrict__ done) {
  __shared__ __align__(16) float red[2][5][4];  // score partials (scan only)

  if (blockIdx.x < 8) {
    // ---------------- scan: 4 waves, wave w owns dims [128w,128w+128) ------
    int b = blockIdx.x;
    int tid = threadIdx.x;
    int w = tid >> 6;
    int lane = tid & 63;
    int dbase = w * 128 + lane * 2;
    int bb = b * 16;
    const float* ob  = O   + (size_t)b * Tq * Dq;
    const float* Gb  = Gm  + (size_t)b * Tq * Dq;
    const float* Pgb = Pg  + (size_t)b * Tq * Dq;
    const float* pmb = out + (size_t)b * Tq * Dq;  // PRE_mlp lives in d_out
    float* po = out + (size_t)b * Tq * Dq;

    int bandReady = -1;
    wait_band(done, bb + 0, 6);
    bandReady = 0;
    __builtin_amdgcn_sched_barrier(0);

    float2 ow[8], gw[8], pm[8], pg[8];
    float2 st = make_float2(0.f, 0.f);
#pragma unroll
    for (int r = 0; r < 5; r++) {
      ow[r] = *(const float2*)(ob  + (size_t)r * Dq + dbase);
      gw[r] = *(const float2*)(Gb  + (size_t)r * Dq + dbase);
      pm[r] = *(const float2*)(pmb + (size_t)r * Dq + dbase);
      pg[r] = *(const float2*)(Pgb + (size_t)r * Dq + dbase);
    }

#define SS(t_, m3_, m4_, A,B,C,D,E, SL_, LW_)                                  \
    scan_step4<A,B,C,D,E, SL_, LW_>(t_, m3_, m4_, lane, w, dbase, ob, Gb,      \
        Pgb, pmb, po, red, done, bb, bandReady, ow, gw, pm, pg, st)

    SS(0, 0.f, 0.f, 0,1,2,3,4, 0, 5);
    SS(1, 1.f, 0.f, 0,1,2,3,4, 1, 6);
    for (int tb = 2; tb <= 2034; tb += 8) {
      SS(tb+0, 1.f, 1.f, 0,1,2,3,4, 2, 7);
      SS(tb+1, 1.f, 1.f, 1,2,3,4,5, 3, 0);
      SS(tb+2, 1.f, 1.f, 2,3,4,5,6, 4, 1);
      SS(tb+3, 1.f, 1.f, 3,4,5,6,7, 5, 2);
      SS(tb+4, 1.f, 1.f, 4,5,6,7,0, 6, 3);
      SS(tb+5, 1.f, 1.f, 5,6,7,0,1, 7, 4);
      SS(tb+6, 1.f, 1.f, 6,7,0,1,2, 0, 5);
      SS(tb+7, 1.f, 1.f, 7,0,1,2,3, 1, 6);
    }
    SS(2042, 1.f, 1.f, 0,1,2,3,4, 2, 7);
    SS(2043, 1.f, 1.f, 1,2,3,4,5, 3, 0);
    SS(2044, 1.f, 1.f, 2,3,4,5,6, 4, 1);
    SS(2045, 1.f, 1.f, 3,4,5,6,7, 5, 2);
    SS(2046, 1.f, 0.f, 4,5,6,7,0, 6, 3);
    SS(2047, 0.f, 0.f, 5,6,7,0,1, 7, 4);
#undef SS
    return;
  }

  // ---------------- paired GEMM producer ------------------------------------
  int g = blockIdx.x - 8;
  int band = g / 48;
  int rem = g % 48;
  int bat = rem / 6;
  int pr = rem % 6;               // 0..3: mode0 by={2pr,2pr+1}; 4..5: mode1
  int bt0 = (bat * 16 + band) * 128;
  int gb = bat * Tq;
  int t0 = bt0 % Tq;

  int tid = threadIdx.x;
  int l = tid & 63, w = tid >> 6;
  int wm = w >> 1, wn = w & 1;
  int r16 = l & 15, kg = l >> 4;

  // Throttle: stay <=2 bands ahead of the slowest scan (advisory L3 window).
  if (band > 2) {
    if (tid == 0) {
      int it = 0;
      for (;;) {
        int smin = 0x7fffffff;
#pragma unroll
        for (int bi = 0; bi < 8; bi++) {
          int v = __hip_atomic_load(&done[SPROG_BASE + bi], __ATOMIC_RELAXED,
                                    __HIP_MEMORY_SCOPE_AGENT);
          smin = v < smin ? v : smin;
        }
        if (smin >= band - 2 || ++it > (1 << 20)) break;
        __builtin_amdgcn_s_sleep(8);
      }
    }
    __syncthreads();
  }

  const f16x8 zz = {0, 0, 0, 0, 0, 0, 0, 0};

  if (pr >= 4) {
    // ---- MODE 1 pair: G = O @ Wg[:, 2560:]^T, by = 2(pr-4)+sub ----
#pragma unroll
    for (int sub = 0; sub < 2; sub++) {
      int by = 2 * (pr - 4) + sub;
      f32x4 acc[4][4] = {};
      const ushort *bph[4], *bpl[4];
      int ncol[4];
#pragma unroll
      for (int ni = 0; ni < 4; ni++) {
        int n_g = by * 128 + wn * 64 + ni * 16 + r16;
        ncol[ni] = n_g;
        size_t off = (size_t)n_g * 3072 + 2560 + kg * 8;
        bph[ni] = Wgh + off; bpl[ni] = Wgl + off;
      }
      const float* ap[4];
#pragma unroll
      for (int mi = 0; mi < 4; mi++) {
        ap[mi] = O + (size_t)(bt0 + wm * 64 + mi * 16 + r16) * Dq + kg * 8;
      }
#pragma unroll 4
      for (int ks = 0; ks < 16; ks++) {
        f16x8 Ah[4], Al[4], Bh[4], Bl[4];
#pragma unroll
        for (int mi = 0; mi < 4; mi++) {
          float4 v0 = *(const float4*)ap[mi];
          float4 v1 = *(const float4*)(ap[mi] + 4);
          ap[mi] += 32;
          split8(v0, v1, Ah[mi], Al[mi]);
        }
#pragma unroll
        for (int ni = 0; ni < 4; ni++) {
          Bh[ni] = *(const f16x8*)bph[ni]; bph[ni] += 32;
          Bl[ni] = *(const f16x8*)bpl[ni]; bpl[ni] += 32;
        }
#pragma unroll
        for (int mi = 0; mi < 4; mi++)
#pragma unroll
          for (int ni = 0; ni < 4; ni++) {
            acc[mi][ni] = __builtin_amdgcn_mfma_f32_16x16x32_f16(Ah[mi], Bh[ni], acc[mi][ni], 0, 0, 0);
            acc[mi][ni] = __builtin_amdgcn_mfma_f32_16x16x32_f16(Al[mi], Bh[ni], acc[mi][ni], 0, 0, 0);
            acc[mi][ni] = __builtin_amdgcn_mfma_f32_16x16x32_f16(Ah[mi], Bl[ni], acc[mi][ni], 0, 0, 0);
          }
      }
      const float SC = 1.0f / 65536.0f;
#pragma unroll
      for (int ni = 0; ni < 4; ni++) {
#pragma unroll
        for (int mi = 0; mi < 4; mi++) {
          int rowb = bt0 + wm * 64 + mi * 16 + kg * 4;
#pragma unroll
          for (int rr = 0; rr < 4; rr++)
            Gm[(size_t)(rowb + rr) * Dq + ncol[ni]] = acc[mi][ni][rr] * SC;
        }
      }
    }
  } else {
    // ---- MODE 0 pair: PRE, by = 2pr+sub (pairs never straddle Pm/Pg) ----
    int arow[4][5];
    uint vmask[4];
#pragma unroll
    for (int mi = 0; mi < 4; mi++) {
      int t = t0 + wm * 64 + mi * 16 + r16;
      int sh = 2 - t; if (sh < 0) sh = 0;
      int hi2 = t + 2; if (hi2 > Tq - 1) hi2 = Tq - 1;
      int lo2 = t - 2; if (lo2 < 0) lo2 = 0;
      int nv = hi2 - lo2 + 1;
      uint vm = 0;
#pragma unroll
      for (int j = 0; j < 5; j++) {
        int r = t - 2 + j + sh;
        if (r > Tq - 1) r = Tq - 1;
        arow[mi][j] = gb + r;
        if (j < nv) vm |= (1u << j);
      }
      vmask[mi] = vm;
    }
#pragma unroll
    for (int sub = 0; sub < 2; sub++) {
      int by = 2 * pr + sub;
      f32x4 acc[4][4] = {};
      const ushort *bph[4], *bpl[4];
      int ncol[4];
#pragma unroll
      for (int ni = 0; ni < 4; ni++) {
        int n_g = by * 128 + wn * 64 + ni * 16 + r16;
        ncol[ni] = n_g;
        size_t off;
        if (by < 4) { off = (size_t)n_g * 2560 + kg * 8; bph[ni] = Wmh + off; bpl[ni] = Wml + off; }
        else { off = (size_t)(n_g - 512) * 3072 + kg * 8; bph[ni] = Wgh + off; bpl[ni] = Wgl + off; }
      }
#pragma unroll
      for (int j = 0; j < 5; j++) {
        const float* ap[4];
        bool v[4];
#pragma unroll
        for (int mi = 0; mi < 4; mi++) {
          ap[mi] = O + (size_t)arow[mi][j] * Dq + kg * 8;
          v[mi] = (vmask[mi] >> j) & 1u;
        }
#pragma unroll 4
        for (int ks = 0; ks < 16; ks++) {
          f16x8 Ah[4], Al[4], Bh[4], Bl[4];
#pragma unroll
          for (int mi = 0; mi < 4; mi++) {
            float4 v0 = *(const float4*)ap[mi];
            float4 v1 = *(const float4*)(ap[mi] + 4);
            ap[mi] += 32;
            f16x8 th, tl;
            split8(v0, v1, th, tl);
            Ah[mi] = v[mi] ? th : zz;
            Al[mi] = v[mi] ? tl : zz;
          }
#pragma unroll
          for (int ni = 0; ni < 4; ni++) {
            Bh[ni] = *(const f16x8*)bph[ni]; bph[ni] += 32;
            Bl[ni] = *(const f16x8*)bpl[ni]; bpl[ni] += 32;
          }
#pragma unroll
          for (int mi = 0; mi < 4; mi++)
#pragma unroll
            for (int ni = 0; ni < 4; ni++) {
              acc[mi][ni] = __builtin_amdgcn_mfma_f32_16x16x32_f16(Ah[mi], Bh[ni], acc[mi][ni], 0, 0, 0);
              acc[mi][ni] = __builtin_amdgcn_mfma_f32_16x16x32_f16(Al[mi], Bh[ni], acc[mi][ni], 0, 0, 0);
              acc[mi][ni] = __builtin_amdgcn_mfma_f32_16x16x32_f16(Ah[mi], Bl[ni], acc[mi][ni], 0, 0, 0);
            }
        }
      }
      const float SC = 1.0f / 65536.0f;
      float* dst = (by < 4) ? out : Pg;  // PRE_mlp -> d_out, PRE_gate -> ws
      const float* bias = (by < 4) ? bm : bg;
#pragma unroll
      for (int ni = 0; ni < 4; ni++) {
        int oc = (by < 4) ? ncol[ni] : ncol[ni] - 512;
        float bi = bias[oc];
#pragma unroll
        for (int mi = 0; mi < 4; mi++) {
          int rowb = bt0 + wm * 64 + mi * 16 + kg * 4;
#pragma unroll
          for (int rr = 0; rr < 4; rr++)
            dst[(size_t)(rowb + rr) * Dq + oc] = fmaf(acc[mi][ni][rr], SC, bi);
        }
      }
    }
  }

  // ---- publish: all stores visible, then bump the band counter ----
  __threadfence();
  __syncthreads();
  if (tid == 0) {
    __hip_atomic_fetch_add(&done[bat * 16 + band], 1, __ATOMIC_RELEASE,
                           __HIP_MEMORY_SCOPE_AGENT);
  }
}

// ---------------------------------------------------------------------------
// f32 fallback (ws too small) — R1-verified serial GEMM + 4-wave scan.
// ---------------------------------------------------------------------------
__global__ __launch_bounds__(256) void gemm_pre(
    const float* __restrict__ O, const float* __restrict__ Wm,
    const float* __restrict__ Wg, const float* __restrict__ bm,
    const float* __restrict__ bg, float* __restrict__ Pm,
    float* __restrict__ Pg, float* __restrict__ Gm, int mode) {
  const int BM = 128, BN = 128, BK = 16;
  __shared__ float As[BK][132];
  __shared__ float Bs[BK][132];
  int tidx = threadIdx.x;
  int bt0 = blockIdx.x * BM;
  int b = bt0 / Tq;
  int t0 = bt0 % Tq;
  int n0 = blockIdx.y * BN;
  int K = mode ? Dq : 5 * Dq;
  int tx = tidx % 16, ty = tidx / 16, lr = tidx >> 2, lc = (tidx & 3) * 4;
  float acc[8][8];
#pragma unroll
  for (int i = 0; i < 8; i++)
#pragma unroll
    for (int j = 0; j < 8; j++) acc[i][j] = 0.f;
  for (int kb = 0; kb < K; kb += BK) {
#pragma unroll
    for (int h = 0; h < 2; h++) {
      int m = lr + h * 64;
      int t = t0 + m;
      float4 av;
      if (mode == 0) {
        int j = kb >> 9;
        int kcol = (kb & 511) + lc;
        int sh = 2 - t; if (sh < 0) sh = 0;
        int r = t - 2 + j + sh;
        int hi = t + 2; if (hi > Tq - 1) hi = Tq - 1;
        int lo2 = t - 2; if (lo2 < 0) lo2 = 0;
        int nv = hi - lo2 + 1;
        if (j < nv) av = *reinterpret_cast<const float4*>(O + ((size_t)b * Tq + r) * Dq + kcol);
        else av = make_float4(0.f, 0.f, 0.f, 0.f);
      } else {
        av = *reinterpret_cast<const float4*>(O + ((size_t)b * Tq + t) * Dq + kb + lc);
      }
      As[lc + 0][m] = av.x; As[lc + 1][m] = av.y;
      As[lc + 2][m] = av.z; As[lc + 3][m] = av.w;
    }
#pragma unroll
    for (int h = 0; h < 2; h++) {
      int n = lr + h * 64;
      int gn = n0 + n;
      const float* wrow;
      int col;
      if (mode == 0) {
        if (gn < 512) { wrow = Wm + (size_t)gn * 2560; col = kb + lc; }
        else          { wrow = Wg + (size_t)(gn - 512) * 3072; col = kb + lc; }
      } else {
        wrow = Wg + (size_t)gn * 3072; col = 2560 + kb + lc;
      }
      float4 bv = *reinterpret_cast<const float4*>(wrow + col);
      Bs[lc + 0][n] = bv.x; Bs[lc + 1][n] = bv.y;
      Bs[lc + 2][n] = bv.z; Bs[lc + 3][n] = bv.w;
    }
    __syncthreads();
#pragma unroll
    for (int kk = 0; kk < BK; kk++) {
      float a[8], bb[8];
      float4 a0 = *reinterpret_cast<float4*>(&As[kk][ty * 8]);
      float4 a1 = *reinterpret_cast<float4*>(&As[kk][ty * 8 + 4]);
      float4 b0 = *reinterpret_cast<float4*>(&Bs[kk][tx * 8]);
      float4 b1 = *reinterpret_cast<float4*>(&Bs[kk][tx * 8 + 4]);
      a[0]=a0.x; a[1]=a0.y; a[2]=a0.z; a[3]=a0.w; a[4]=a1.x; a[5]=a1.y; a[6]=a1.z; a[7]=a1.w;
      bb[0]=b0.x; bb[1]=b0.y; bb[2]=b0.z; bb[3]=b0.w; bb[4]=b1.x; bb[5]=b1.y; bb[6]=b1.z; bb[7]=b1.w;
#pragma unroll
      for (int i = 0; i < 8; i++)
#pragma unroll
        for (int j = 0; j < 8; j++) acc[i][j] = fmaf(a[i], bb[j], acc[i][j]);
    }
    __syncthreads();
  }
  int gn = n0 + tx * 8;
  float bias[8];
  float* dstbase;
  int coloff;
  if (mode == 0) {
    if (gn < 512) {
#pragma unroll
      for (int j = 0; j < 8; j++) bias[j] = bm[gn + j];
      dstbase = Pm; coloff = gn;
    } else {
#pragma unroll
      for (int j = 0; j < 8; j++) bias[j] = bg[gn - 512 + j];
      dstbase = Pg; coloff = gn - 512;
    }
  } else {
#pragma unroll
    for (int j = 0; j < 8; j++) bias[j] = 0.f;
    dstbase = Gm; coloff = gn;
  }
#pragma unroll
  for (int i = 0; i < 8; i++) {
    int bt = bt0 + ty * 8 + i;
    float4 v0 = make_float4(acc[i][0] + bias[0], acc[i][1] + bias[1],
                            acc[i][2] + bias[2], acc[i][3] + bias[3]);
    float4 v1 = make_float4(acc[i][4] + bias[4], acc[i][5] + bias[5],
                            acc[i][6] + bias[6], acc[i][7] + bias[7]);
    float4* d = reinterpret_cast<float4*>(dstbase + (size_t)bt * Dq + coloff);
    d[0] = v0;
    d[1] = v1;
  }
}

// Fallback serial 4-wave scan (done[] pre-filled >= 6 so gates are no-ops).
__global__ __launch_bounds__(256, 1) void scan_only(
    const float* __restrict__ O, const float* __restrict__ Gm,
    const float* __restrict__ Pg, const float* __restrict__ Pm,
    float* __restrict__ out, int* __restrict__ done) {
  __shared__ __align__(16) float red[2][5][4];
  int b = blockIdx.x;
  int tid = threadIdx.x;
  int w = tid >> 6;
  int lane = tid & 63;
  int dbase = w * 128 + lane * 2;
  int bb = b * 16;
  const float* ob  = O  + (size_t)b * Tq * Dq;
  const float* Gb  = Gm + (size_t)b * Tq * Dq;
  const float* Pgb = Pg + (size_t)b * Tq * Dq;
  const float* pmb = Pm + (size_t)b * Tq * Dq;
  float* po = out + (size_t)b * Tq * Dq;
  int bandReady = 15;

  float2 ow[8], gw[8], pm[8], pg[8];
  float2 st = make_float2(0.f, 0.f);
#pragma unroll
  for (int r = 0; r < 5; r++) {
    ow[r] = *(const float2*)(ob  + (size_t)r * Dq + dbase);
    gw[r] = *(const float2*)(Gb  + (size_t)r * Dq + dbase);
    pm[r] = *(const float2*)(pmb + (size_t)r * Dq + dbase);
    pg[r] = *(const float2*)(Pgb + (size_t)r * Dq + dbase);
  }
#define SS(t_, m3_, m4_, A,B,C,D,E, SL_, LW_)                                  \
  scan_step4<A,B,C,D,E, SL_, LW_>(t_, m3_, m4_, lane, w, dbase, ob, Gb,        \
      Pgb, pmb, po, red, done, bb, bandReady, ow, gw, pm, pg, st)
  SS(0, 0.f, 0.f, 0,1,2,3,4, 0, 5);
  SS(1, 1.f, 0.f, 0,1,2,3,4, 1, 6);
  for (int tb = 2; tb <= 2034; tb += 8) {
    SS(tb+0, 1.f, 1.f, 0,1,2,3,4, 2, 7);
    SS(tb+1, 1.f, 1.f, 1,2,3,4,5, 3, 0);
    SS(tb+2, 1.f, 1.f, 2,3,4,5,6, 4, 1);
    SS(tb+3, 1.f, 1.f, 3,4,5,6,7, 5, 2);
    SS(tb+4, 1.f, 1.f, 4,5,6,7,0, 6, 3);
    SS(tb+5, 1.f, 1.f, 5,6,7,0,1, 7, 4);
    SS(tb+6, 1.f, 1.f, 6,7,0,1,2, 0, 5);
    SS(tb+7, 1.f, 1.f, 7,0,1,2,3, 1, 6);
  }
  SS(2042, 1.f, 1.f, 0,1,2,3,4, 2, 7);
  SS(2043, 1.f, 1.f, 1,2,3,4,5, 3, 0);
  SS(2044, 1.f, 1.f, 2,3,4,5,6, 4, 1);
  SS(2045, 1.f, 1.f, 3,4,5,6,7, 5, 2);
  SS(2046, 1.f, 0.f, 4,5,6,7,0, 6, 3);
  SS(2047, 0.f, 0.f, 5,6,7,0,1, 7, 4);
#undef SS
}

extern "C" void kernel_launch(void* const* d_in, const int* in_sizes, int n_in,
                              void* d_out, int out_size, void* d_ws, size_t ws_size,
                              hipStream_t stream) {
  const float* O  = (const float*)d_in[0];
  const float* Wm = (const float*)d_in[1];
  const float* bm = (const float*)d_in[2];
  const float* Wg = (const float*)d_in[3];
  const float* bg = (const float*)d_in[4];
  float* out = (float*)d_out;

  const size_t NTOT = (size_t)Bq * Tq * Dq;   // 8.39M
  const size_t NWM = 512 * 2560, NWG = 512 * 3072;
  float* Pg = (float*)d_ws;
  float* Gm = Pg + NTOT;
  ushort* WMH = (ushort*)(Gm + NTOT);
  ushort* WML = WMH + NWM;
  ushort* WGH = WML + NWM;
  ushort* WGL = WGH + NWG;
  int* done = (int*)(WGL + NWG);              // 256 ints: [0..127] bands, [128..135] sprog

  size_t need = 2 * NTOT * 4 + 2 * (NWM + NWG) * 2 + 256 * 4;  // ~78.5 MB
  if (ws_size >= need) {
    hipMemsetAsync(done, 0, 256 * 4, stream);
    cvt_f16split<<<dim3((NWM / 8 + 255) / 256), dim3(256), 0, stream>>>(Wm, WMH, WML, NWM / 8);
    cvt_f16split<<<dim3((NWG / 8 + 255) / 256), dim3(256), 0, stream>>>(Wg, WGH, WGL, NWG / 8);
    fused_kernel<<<dim3(8 + 16 * 48), dim3(256), 0, stream>>>(
        O, WMH, WML, WGH, WGL, bm, bg, Pg, Gm, out, done);
  } else {
    bool sep = ws_size >= (size_t)(3 * NTOT * 4 + 256 * 4);
    float* Pm = sep ? (Gm + NTOT) : out;
    int* done2 = sep ? (int*)(Pm + NTOT) : (int*)(Gm + NTOT);
    hipMemsetAsync(done2, 6, 256 * 4, stream);  // every byte 6 -> >= 6
    gemm_pre<<<dim3(128, 8), dim3(256), 0, stream>>>(O, Wm, Wg, bm, bg, Pm, Pg, Gm, 0);
    gemm_pre<<<dim3(128, 4), dim3(256), 0, stream>>>(O, Wm, Wg, bm, bg, Pm, Pg, Gm, 1);
    scan_only<<<dim3(Bq), dim3(256), 0, stream>>>(O, Gm, Pg, Pm, out, done2);
  }
}

// Round 19
// 1813.574 us; speedup vs baseline: 1259.9186x; 3.3500x over previous
//
#include <hip/hip_runtime.h>

#define Bq 8
#define Tq 2048
#define Dq 512

typedef __attribute__((ext_vector_type(8))) _Float16 f16x8;  // 8 f16 = 4 VGPRs
typedef __attribute__((ext_vector_type(8))) short u16x8;
typedef __attribute__((ext_vector_type(4))) float f32x4;

// ---------------------------------------------------------------------------
// f32 -> (hi,lo) f16 split planes, x*256 pre-scale (undone by 2^-16 in GEMM).
// Used only for the (small, reused) weight matrices.
// ---------------------------------------------------------------------------
__global__ __launch_bounds__(256) void cvt_f16split(
    const float* __restrict__ s, ushort* __restrict__ hi,
    ushort* __restrict__ lo, int n8) {
  int i = blockIdx.x * 256 + threadIdx.x;
  if (i >= n8) return;
  const float4* sp = reinterpret_cast<const float4*>(s) + i * 2;
  float4 a = sp[0], b = sp[1];
  float x[8] = {a.x, a.y, a.z, a.w, b.x, b.y, b.z, b.w};
  ushort h[8], l[8];
#pragma unroll
  for (int e = 0; e < 8; e++) {
    float xs = x[e] * 256.0f;
    _Float16 hh = (_Float16)xs;
    _Float16 ll = (_Float16)(xs - (float)hh);
    h[e] = *(ushort*)&hh;
    l[e] = *(ushort*)&ll;
  }
  *reinterpret_cast<u16x8*>(hi + (size_t)i * 8) = *reinterpret_cast<u16x8*>(h);
  *reinterpret_cast<u16x8*>(lo + (size_t)i * 8) = *reinterpret_cast<u16x8*>(l);
}

// In-register split of 8 f32 into hi/lo f16 planes — same elementwise math as
// cvt_f16split (R16-verified bit-identical PRE, absmax 0.0078).
__device__ __forceinline__ void split8(const float4& a, const float4& b,
                                       f16x8& hi, f16x8& lo) {
  float x[8] = {a.x, a.y, a.z, a.w, b.x, b.y, b.z, b.w};
#pragma unroll
  for (int e = 0; e < 8; e++) {
    float xs = x[e] * 256.0f;
    _Float16 hh = (_Float16)xs;
    _Float16 ll = (_Float16)(xs - (float)hh);
    hi[e] = hh;
    lo[e] = ll;
  }
}

// ===========================================================================
// Common helpers.
// ===========================================================================
template <int CTRL>
__device__ __forceinline__ float dppadd(float v) {
  int r = __builtin_amdgcn_update_dpp(0, __float_as_int(v), CTRL, 0xF, 0xF, true);
  return v + __int_as_float(r);
}
__device__ __forceinline__ float wave_sum_bcast(float v) {
  v = dppadd<0x111>(v);
  v = dppadd<0x112>(v);
  v = dppadd<0x114>(v);
  v = dppadd<0x118>(v);
  v = dppadd<0x142>(v);
  v = dppadd<0x143>(v);
  return __int_as_float(__builtin_amdgcn_readlane(__float_as_int(v), 63));
}

// Bounded agent-scope wait on a monotone counter (bug -> absmax fail, not hang).
__device__ __forceinline__ void wait_band(int* done, int idx, int target) {
  int it = 0;
  while (__hip_atomic_load(&done[idx], __ATOMIC_ACQUIRE,
                           __HIP_MEMORY_SCOPE_AGENT) < target) {
    __builtin_amdgcn_s_sleep(8);
    if (++it > (1 << 22)) break;
  }
}

// ===========================================================================
// 4-wave cooperative scan step — R15/R16-verified (absmax 0.0078). NUMERICS
// ARE R5's EXACT ORDER. Do not re-derive (R14 lesson: ulp-level reordering
// diverges chaotically). R18 lesson: NO producer throttling (convoy collapse:
// 48-96 active producer blocks starve the GPU; free-running producers finish
// in ~650us and the scan gates are then all no-ops).
// ===========================================================================
template <int S0, int S1, int S2, int S3, int S4, int SLOT, int SLW>
__device__ __forceinline__ void scan_step4(
    int t, float m3, float m4, int lane, int w, int dbase,
    const float* __restrict__ ob, const float* __restrict__ Gb,
    const float* __restrict__ Pgb, const float* __restrict__ pmb,
    float* __restrict__ po, float (*red)[5][4],
    int* done, int bb, int& bandReady,
    float2 (&ow)[8], float2 (&gw)[8], float2 (&pm)[8], float2 (&pg)[8],
    float2& st) {
  int rw = t + 5; if (rw > Tq - 1) rw = Tq - 1;
  int band = rw >> 7;
  if (band > bandReady) {  // once per 128 steps: gate on producer progress
    wait_band(done, bb + band, 6);
    bandReady = band;
  }
  __builtin_amdgcn_sched_barrier(0);
  ow[SLW] = *(const float2*)(ob  + (size_t)rw * Dq + dbase);
  gw[SLW] = *(const float2*)(Gb  + (size_t)rw * Dq + dbase);
  pm[SLW] = *(const float2*)(pmb + (size_t)rw * Dq + dbase);
  pg[SLW] = *(const float2*)(Pgb + (size_t)rw * Dq + dbase);
  __builtin_amdgcn_sched_barrier(0);

  // ---- partial scores over this wave's 128 dims (R5-exact) ----
  const float scale = 0.04419417382415922f;  // 1/sqrt(512)
  float s0 = st.x * ow[S0].x; s0 = fmaf(st.y, ow[S0].y, s0);
  float s1 = st.x * ow[S1].x; s1 = fmaf(st.y, ow[S1].y, s1);
  float s2 = st.x * ow[S2].x; s2 = fmaf(st.y, ow[S2].y, s2);
  float s3 = st.x * ow[S3].x; s3 = fmaf(st.y, ow[S3].y, s3);
  float s4 = st.x * ow[S4].x; s4 = fmaf(st.y, ow[S4].y, s4);
  s0 = wave_sum_bcast(s0);
  s1 = wave_sum_bcast(s1);
  s2 = wave_sum_bcast(s2);
  s3 = wave_sum_bcast(s3);
  s4 = wave_sum_bcast(s4);
  s0 *= scale; s1 *= scale; s2 *= scale;
  s3 *= scale * m3;  // masked scores -> exact 0
  s4 *= scale * m4;

  float pv = s0;
  pv = (lane == 1) ? s1 : pv;
  pv = (lane == 2) ? s2 : pv;
  pv = (lane == 3) ? s3 : pv;
  pv = (lane == 4) ? s4 : pv;
  if (lane < 5) red[t & 1][lane][w] = pv;

  asm volatile("s_waitcnt lgkmcnt(0)" ::: "memory");
  __builtin_amdgcn_sched_barrier(0);
  __builtin_amdgcn_s_barrier();   // raw: no compiler vmcnt(0) drain
  __builtin_amdgcn_sched_barrier(0);

  // ---- full scores + softmax (R5-exact) ----
  float fs[5];
#pragma unroll
  for (int j = 0; j < 5; j++) {
    float4 rv = *(const float4*)(&red[t & 1][j][0]);
    fs[j] = (rv.x + rv.y) + (rv.z + rv.w);
  }
  float mx = fmaxf(fmaxf(fmaxf(fs[0], fs[1]), fmaxf(fs[2], fs[3])), fs[4]);
  float e0 = __expf(fs[0] - mx), e1 = __expf(fs[1] - mx), e2 = __expf(fs[2] - mx);
  float e3 = __expf(fs[3] - mx), e4 = __expf(fs[4] - mx);
  float inv = __fdividef(1.0f, e0 + e1 + e2 + e3 + e4);
  float q0 = e0 * inv, q1 = e1 * inv, q2 = e2 * inv;
  float q3 = e3 * inv * m3, q4 = e4 * inv * m4;  // padded rows contribute 0

  // ---- weighted sums, gate, state update (R5-exact fma chains) ----
  float ax = q0 * ow[S0].x; ax = fmaf(q1, ow[S1].x, ax); ax = fmaf(q2, ow[S2].x, ax);
  ax = fmaf(q3, ow[S3].x, ax); ax = fmaf(q4, ow[S4].x, ax);
  float ay = q0 * ow[S0].y; ay = fmaf(q1, ow[S1].y, ay); ay = fmaf(q2, ow[S2].y, ay);
  ay = fmaf(q3, ow[S3].y, ay); ay = fmaf(q4, ow[S4].y, ay);
  float gx = q0 * gw[S0].x; gx = fmaf(q1, gw[S1].x, gx); gx = fmaf(q2, gw[S2].x, gx);
  gx = fmaf(q3, gw[S3].x, gx); gx = fmaf(q4, gw[S4].x, gx);
  float gy = q0 * gw[S0].y; gy = fmaf(q1, gw[S1].y, gy); gy = fmaf(q2, gw[S2].y, gy);
  gy = fmaf(q3, gw[S3].y, gy); gy = fmaf(q4, gw[S4].y, gy);

  float2 ot;
  ot.x = fmaf(ax, __fdividef(1.f, 1.f + __expf(-(pg[SLOT].x + gx))), pm[SLOT].x);
  ot.y = fmaf(ay, __fdividef(1.f, 1.f + __expf(-(pg[SLOT].y + gy))), pm[SLOT].y);
  st = ot;
  *(float2*)(po + (size_t)t * Dq + dbase) = ot;
}

// ===========================================================================
// FUSED kernel: blocks 0..7 = per-batch 4-wave scans; blocks 8.. = paired
// free-running GEMM producers (band-major; 48 blocks/band; each runs 2
// same-mode by-roles back-to-back for A-reuse; done[b*16+band] target 6).
// ===========================================================================
__global__ __launch_bounds__(256, 1) void fused_kernel(
    const float* __restrict__ O,
    const ushort* __restrict__ Wmh, const ushort* __restrict__ Wml,
    const ushort* __restrict__ Wgh, const ushort* __restrict__ Wgl,
    const float* __restrict__ bm, const float* __restrict__ bg,
    float* __restrict__ Pg, float* __restrict__ Gm,
    float* __restrict__ out, int* __restrict__ done) {
  __shared__ __align__(16) float red[2][5][4];  // score partials (scan only)

  if (blockIdx.x < 8) {
    // ---------------- scan: 4 waves, wave w owns dims [128w,128w+128) ------
    int b = blockIdx.x;
    int tid = threadIdx.x;
    int w = tid >> 6;
    int lane = tid & 63;
    int dbase = w * 128 + lane * 2;
    int bb = b * 16;
    const float* ob  = O   + (size_t)b * Tq * Dq;
    const float* Gb  = Gm  + (size_t)b * Tq * Dq;
    const float* Pgb = Pg  + (size_t)b * Tq * Dq;
    const float* pmb = out + (size_t)b * Tq * Dq;  // PRE_mlp lives in d_out
    float* po = out + (size_t)b * Tq * Dq;

    int bandReady = -1;
    wait_band(done, bb + 0, 6);
    bandReady = 0;
    __builtin_amdgcn_sched_barrier(0);

    float2 ow[8], gw[8], pm[8], pg[8];
    float2 st = make_float2(0.f, 0.f);
#pragma unroll
    for (int r = 0; r < 5; r++) {
      ow[r] = *(const float2*)(ob  + (size_t)r * Dq + dbase);
      gw[r] = *(const float2*)(Gb  + (size_t)r * Dq + dbase);
      pm[r] = *(const float2*)(pmb + (size_t)r * Dq + dbase);
      pg[r] = *(const float2*)(Pgb + (size_t)r * Dq + dbase);
    }

#define SS(t_, m3_, m4_, A,B,C,D,E, SL_, LW_)                                  \
    scan_step4<A,B,C,D,E, SL_, LW_>(t_, m3_, m4_, lane, w, dbase, ob, Gb,      \
        Pgb, pmb, po, red, done, bb, bandReady, ow, gw, pm, pg, st)

    SS(0, 0.f, 0.f, 0,1,2,3,4, 0, 5);
    SS(1, 1.f, 0.f, 0,1,2,3,4, 1, 6);
    for (int tb = 2; tb <= 2034; tb += 8) {
      SS(tb+0, 1.f, 1.f, 0,1,2,3,4, 2, 7);
      SS(tb+1, 1.f, 1.f, 1,2,3,4,5, 3, 0);
      SS(tb+2, 1.f, 1.f, 2,3,4,5,6, 4, 1);
      SS(tb+3, 1.f, 1.f, 3,4,5,6,7, 5, 2);
      SS(tb+4, 1.f, 1.f, 4,5,6,7,0, 6, 3);
      SS(tb+5, 1.f, 1.f, 5,6,7,0,1, 7, 4);
      SS(tb+6, 1.f, 1.f, 6,7,0,1,2, 0, 5);
      SS(tb+7, 1.f, 1.f, 7,0,1,2,3, 1, 6);
    }
    SS(2042, 1.f, 1.f, 0,1,2,3,4, 2, 7);
    SS(2043, 1.f, 1.f, 1,2,3,4,5, 3, 0);
    SS(2044, 1.f, 1.f, 2,3,4,5,6, 4, 1);
    SS(2045, 1.f, 1.f, 3,4,5,6,7, 5, 2);
    SS(2046, 1.f, 0.f, 4,5,6,7,0, 6, 3);
    SS(2047, 0.f, 0.f, 5,6,7,0,1, 7, 4);
#undef SS
    return;
  }

  // ---------------- paired free-running GEMM producer -----------------------
  int g = blockIdx.x - 8;
  int band = g / 48;
  int rem = g % 48;
  int bat = rem / 6;
  int pr = rem % 6;               // 0..3: mode0 by={2pr,2pr+1}; 4..5: mode1
  int bt0 = (bat * 16 + band) * 128;
  int gb = bat * Tq;
  int t0 = bt0 % Tq;

  int tid = threadIdx.x;
  int l = tid & 63, w = tid >> 6;
  int wm = w >> 1, wn = w & 1;
  int r16 = l & 15, kg = l >> 4;

  const f16x8 zz = {0, 0, 0, 0, 0, 0, 0, 0};

  if (pr >= 4) {
    // ---- MODE 1 pair: G = O @ Wg[:, 2560:]^T, by = 2(pr-4)+sub ----
#pragma unroll
    for (int sub = 0; sub < 2; sub++) {
      int by = 2 * (pr - 4) + sub;
      f32x4 acc[4][4] = {};
      const ushort *bph[4], *bpl[4];
      int ncol[4];
#pragma unroll
      for (int ni = 0; ni < 4; ni++) {
        int n_g = by * 128 + wn * 64 + ni * 16 + r16;
        ncol[ni] = n_g;
        size_t off = (size_t)n_g * 3072 + 2560 + kg * 8;
        bph[ni] = Wgh + off; bpl[ni] = Wgl + off;
      }
      const float* ap[4];
#pragma unroll
      for (int mi = 0; mi < 4; mi++) {
        ap[mi] = O + (size_t)(bt0 + wm * 64 + mi * 16 + r16) * Dq + kg * 8;
      }
#pragma unroll 4
      for (int ks = 0; ks < 16; ks++) {
        f16x8 Ah[4], Al[4], Bh[4], Bl[4];
#pragma unroll
        for (int mi = 0; mi < 4; mi++) {
          float4 v0 = *(const float4*)ap[mi];
          float4 v1 = *(const float4*)(ap[mi] + 4);
          ap[mi] += 32;
          split8(v0, v1, Ah[mi], Al[mi]);
        }
#pragma unroll
        for (int ni = 0; ni < 4; ni++) {
          Bh[ni] = *(const f16x8*)bph[ni]; bph[ni] += 32;
          Bl[ni] = *(const f16x8*)bpl[ni]; bpl[ni] += 32;
        }
#pragma unroll
        for (int mi = 0; mi < 4; mi++)
#pragma unroll
          for (int ni = 0; ni < 4; ni++) {
            acc[mi][ni] = __builtin_amdgcn_mfma_f32_16x16x32_f16(Ah[mi], Bh[ni], acc[mi][ni], 0, 0, 0);
            acc[mi][ni] = __builtin_amdgcn_mfma_f32_16x16x32_f16(Al[mi], Bh[ni], acc[mi][ni], 0, 0, 0);
            acc[mi][ni] = __builtin_amdgcn_mfma_f32_16x16x32_f16(Ah[mi], Bl[ni], acc[mi][ni], 0, 0, 0);
          }
      }
      const float SC = 1.0f / 65536.0f;
#pragma unroll
      for (int ni = 0; ni < 4; ni++) {
#pragma unroll
        for (int mi = 0; mi < 4; mi++) {
          int rowb = bt0 + wm * 64 + mi * 16 + kg * 4;
#pragma unroll
          for (int rr = 0; rr < 4; rr++)
            Gm[(size_t)(rowb + rr) * Dq + ncol[ni]] = acc[mi][ni][rr] * SC;
        }
      }
    }
  } else {
    // ---- MODE 0 pair: PRE, by = 2pr+sub (pairs never straddle Pm/Pg) ----
    int arow[4][5];
    uint vmask[4];
#pragma unroll
    for (int mi = 0; mi < 4; mi++) {
      int t = t0 + wm * 64 + mi * 16 + r16;
      int sh = 2 - t; if (sh < 0) sh = 0;
      int hi2 = t + 2; if (hi2 > Tq - 1) hi2 = Tq - 1;
      int lo2 = t - 2; if (lo2 < 0) lo2 = 0;
      int nv = hi2 - lo2 + 1;
      uint vm = 0;
#pragma unroll
      for (int j = 0; j < 5; j++) {
        int r = t - 2 + j + sh;
        if (r > Tq - 1) r = Tq - 1;
        arow[mi][j] = gb + r;
        if (j < nv) vm |= (1u << j);
      }
      vmask[mi] = vm;
    }
#pragma unroll
    for (int sub = 0; sub < 2; sub++) {
      int by = 2 * pr + sub;
      f32x4 acc[4][4] = {};
      const ushort *bph[4], *bpl[4];
      int ncol[4];
#pragma unroll
      for (int ni = 0; ni < 4; ni++) {
        int n_g = by * 128 + wn * 64 + ni * 16 + r16;
        ncol[ni] = n_g;
        size_t off;
        if (by < 4) { off = (size_t)n_g * 2560 + kg * 8; bph[ni] = Wmh + off; bpl[ni] = Wml + off; }
        else { off = (size_t)(n_g - 512) * 3072 + kg * 8; bph[ni] = Wgh + off; bpl[ni] = Wgl + off; }
      }
#pragma unroll
      for (int j = 0; j < 5; j++) {
        const float* ap[4];
        bool v[4];
#pragma unroll
        for (int mi = 0; mi < 4; mi++) {
          ap[mi] = O + (size_t)arow[mi][j] * Dq + kg * 8;
          v[mi] = (vmask[mi] >> j) & 1u;
        }
#pragma unroll 4
        for (int ks = 0; ks < 16; ks++) {
          f16x8 Ah[4], Al[4], Bh[4], Bl[4];
#pragma unroll
          for (int mi = 0; mi < 4; mi++) {
            float4 v0 = *(const float4*)ap[mi];
            float4 v1 = *(const float4*)(ap[mi] + 4);
            ap[mi] += 32;
            f16x8 th, tl;
            split8(v0, v1, th, tl);
            Ah[mi] = v[mi] ? th : zz;
            Al[mi] = v[mi] ? tl : zz;
          }
#pragma unroll
          for (int ni = 0; ni < 4; ni++) {
            Bh[ni] = *(const f16x8*)bph[ni]; bph[ni] += 32;
            Bl[ni] = *(const f16x8*)bpl[ni]; bpl[ni] += 32;
          }
#pragma unroll
          for (int mi = 0; mi < 4; mi++)
#pragma unroll
            for (int ni = 0; ni < 4; ni++) {
              acc[mi][ni] = __builtin_amdgcn_mfma_f32_16x16x32_f16(Ah[mi], Bh[ni], acc[mi][ni], 0, 0, 0);
              acc[mi][ni] = __builtin_amdgcn_mfma_f32_16x16x32_f16(Al[mi], Bh[ni], acc[mi][ni], 0, 0, 0);
              acc[mi][ni] = __builtin_amdgcn_mfma_f32_16x16x32_f16(Ah[mi], Bl[ni], acc[mi][ni], 0, 0, 0);
            }
        }
      }
      const float SC = 1.0f / 65536.0f;
      float* dst = (by < 4) ? out : Pg;  // PRE_mlp -> d_out, PRE_gate -> ws
      const float* bias = (by < 4) ? bm : bg;
#pragma unroll
      for (int ni = 0; ni < 4; ni++) {
        int oc = (by < 4) ? ncol[ni] : ncol[ni] - 512;
        float bi = bias[oc];
#pragma unroll
        for (int mi = 0; mi < 4; mi++) {
          int rowb = bt0 + wm * 64 + mi * 16 + kg * 4;
#pragma unroll
          for (int rr = 0; rr < 4; rr++)
            dst[(size_t)(rowb + rr) * Dq + oc] = fmaf(acc[mi][ni][rr], SC, bi);
        }
      }
    }
  }

  // ---- publish: all stores visible, then bump the band counter ----
  __threadfence();
  __syncthreads();
  if (tid == 0) {
    __hip_atomic_fetch_add(&done[bat * 16 + band], 1, __ATOMIC_RELEASE,
                           __HIP_MEMORY_SCOPE_AGENT);
  }
}

// ---------------------------------------------------------------------------
// f32 fallback (ws too small) — R1-verified serial GEMM + 4-wave scan.
// ---------------------------------------------------------------------------
__global__ __launch_bounds__(256) void gemm_pre(
    const float* __restrict__ O, const float* __restrict__ Wm,
    const float* __restrict__ Wg, const float* __restrict__ bm,
    const float* __restrict__ bg, float* __restrict__ Pm,
    float* __restrict__ Pg, float* __restrict__ Gm, int mode) {
  const int BM = 128, BN = 128, BK = 16;
  __shared__ float As[BK][132];
  __shared__ float Bs[BK][132];
  int tidx = threadIdx.x;
  int bt0 = blockIdx.x * BM;
  int b = bt0 / Tq;
  int t0 = bt0 % Tq;
  int n0 = blockIdx.y * BN;
  int K = mode ? Dq : 5 * Dq;
  int tx = tidx % 16, ty = tidx / 16, lr = tidx >> 2, lc = (tidx & 3) * 4;
  float acc[8][8];
#pragma unroll
  for (int i = 0; i < 8; i++)
#pragma unroll
    for (int j = 0; j < 8; j++) acc[i][j] = 0.f;
  for (int kb = 0; kb < K; kb += BK) {
#pragma unroll
    for (int h = 0; h < 2; h++) {
      int m = lr + h * 64;
      int t = t0 + m;
      float4 av;
      if (mode == 0) {
        int j = kb >> 9;
        int kcol = (kb & 511) + lc;
        int sh = 2 - t; if (sh < 0) sh = 0;
        int r = t - 2 + j + sh;
        int hi = t + 2; if (hi > Tq - 1) hi = Tq - 1;
        int lo2 = t - 2; if (lo2 < 0) lo2 = 0;
        int nv = hi - lo2 + 1;
        if (j < nv) av = *reinterpret_cast<const float4*>(O + ((size_t)b * Tq + r) * Dq + kcol);
        else av = make_float4(0.f, 0.f, 0.f, 0.f);
      } else {
        av = *reinterpret_cast<const float4*>(O + ((size_t)b * Tq + t) * Dq + kb + lc);
      }
      As[lc + 0][m] = av.x; As[lc + 1][m] = av.y;
      As[lc + 2][m] = av.z; As[lc + 3][m] = av.w;
    }
#pragma unroll
    for (int h = 0; h < 2; h++) {
      int n = lr + h * 64;
      int gn = n0 + n;
      const float* wrow;
      int col;
      if (mode == 0) {
        if (gn < 512) { wrow = Wm + (size_t)gn * 2560; col = kb + lc; }
        else          { wrow = Wg + (size_t)(gn - 512) * 3072; col = kb + lc; }
      } else {
        wrow = Wg + (size_t)gn * 3072; col = 2560 + kb + lc;
      }
      float4 bv = *reinterpret_cast<const float4*>(wrow + col);
      Bs[lc + 0][n] = bv.x; Bs[lc + 1][n] = bv.y;
      Bs[lc + 2][n] = bv.z; Bs[lc + 3][n] = bv.w;
    }
    __syncthreads();
#pragma unroll
    for (int kk = 0; kk < BK; kk++) {
      float a[8], bb[8];
      float4 a0 = *reinterpret_cast<float4*>(&As[kk][ty * 8]);
      float4 a1 = *reinterpret_cast<float4*>(&As[kk][ty * 8 + 4]);
      float4 b0 = *reinterpret_cast<float4*>(&Bs[kk][tx * 8]);
      float4 b1 = *reinterpret_cast<float4*>(&Bs[kk][tx * 8 + 4]);
      a[0]=a0.x; a[1]=a0.y; a[2]=a0.z; a[3]=a0.w; a[4]=a1.x; a[5]=a1.y; a[6]=a1.z; a[7]=a1.w;
      bb[0]=b0.x; bb[1]=b0.y; bb[2]=b0.z; bb[3]=b0.w; bb[4]=b1.x; bb[5]=b1.y; bb[6]=b1.z; bb[7]=b1.w;
#pragma unroll
      for (int i = 0; i < 8; i++)
#pragma unroll
        for (int j = 0; j < 8; j++) acc[i][j] = fmaf(a[i], bb[j], acc[i][j]);
    }
    __syncthreads();
  }
  int gn = n0 + tx * 8;
  float bias[8];
  float* dstbase;
  int coloff;
  if (mode == 0) {
    if (gn < 512) {
#pragma unroll
      for (int j = 0; j < 8; j++) bias[j] = bm[gn + j];
      dstbase = Pm; coloff = gn;
    } else {
#pragma unroll
      for (int j = 0; j < 8; j++) bias[j] = bg[gn - 512 + j];
      dstbase = Pg; coloff = gn - 512;
    }
  } else {
#pragma unroll
    for (int j = 0; j < 8; j++) bias[j] = 0.f;
    dstbase = Gm; coloff = gn;
  }
#pragma unroll
  for (int i = 0; i < 8; i++) {
    int bt = bt0 + ty * 8 + i;
    float4 v0 = make_float4(acc[i][0] + bias[0], acc[i][1] + bias[1],
                            acc[i][2] + bias[2], acc[i][3] + bias[3]);
    float4 v1 = make_float4(acc[i][4] + bias[4], acc[i][5] + bias[5],
                            acc[i][6] + bias[6], acc[i][7] + bias[7]);
    float4* d = reinterpret_cast<float4*>(dstbase + (size_t)bt * Dq + coloff);
    d[0] = v0;
    d[1] = v1;
  }
}

// Fallback serial 4-wave scan (done[] pre-filled >= 6 so gates are no-ops).
__global__ __launch_bounds__(256, 1) void scan_only(
    const float* __restrict__ O, const float* __restrict__ Gm,
    const float* __restrict__ Pg, const float* __restrict__ Pm,
    float* __restrict__ out, int* __restrict__ done) {
  __shared__ __align__(16) float red[2][5][4];
  int b = blockIdx.x;
  int tid = threadIdx.x;
  int w = tid >> 6;
  int lane = tid & 63;
  int dbase = w * 128 + lane * 2;
  int bb = b * 16;
  const float* ob  = O  + (size_t)b * Tq * Dq;
  const float* Gb  = Gm + (size_t)b * Tq * Dq;
  const float* Pgb = Pg + (size_t)b * Tq * Dq;
  const float* pmb = Pm + (size_t)b * Tq * Dq;
  float* po = out + (size_t)b * Tq * Dq;
  int bandReady = 15;

  float2 ow[8], gw[8], pm[8], pg[8];
  float2 st = make_float2(0.f, 0.f);
#pragma unroll
  for (int r = 0; r < 5; r++) {
    ow[r] = *(const float2*)(ob  + (size_t)r * Dq + dbase);
    gw[r] = *(const float2*)(Gb  + (size_t)r * Dq + dbase);
    pm[r] = *(const float2*)(pmb + (size_t)r * Dq + dbase);
    pg[r] = *(const float2*)(Pgb + (size_t)r * Dq + dbase);
  }
#define SS(t_, m3_, m4_, A,B,C,D,E, SL_, LW_)                                  \
  scan_step4<A,B,C,D,E, SL_, LW_>(t_, m3_, m4_, lane, w, dbase, ob, Gb,        \
      Pgb, pmb, po, red, done, bb, bandReady, ow, gw, pm, pg, st)
  SS(0, 0.f, 0.f, 0,1,2,3,4, 0, 5);
  SS(1, 1.f, 0.f, 0,1,2,3,4, 1, 6);
  for (int tb = 2; tb <= 2034; tb += 8) {
    SS(tb+0, 1.f, 1.f, 0,1,2,3,4, 2, 7);
    SS(tb+1, 1.f, 1.f, 1,2,3,4,5, 3, 0);
    SS(tb+2, 1.f, 1.f, 2,3,4,5,6, 4, 1);
    SS(tb+3, 1.f, 1.f, 3,4,5,6,7, 5, 2);
    SS(tb+4, 1.f, 1.f, 4,5,6,7,0, 6, 3);
    SS(tb+5, 1.f, 1.f, 5,6,7,0,1, 7, 4);
    SS(tb+6, 1.f, 1.f, 6,7,0,1,2, 0, 5);
    SS(tb+7, 1.f, 1.f, 7,0,1,2,3, 1, 6);
  }
  SS(2042, 1.f, 1.f, 0,1,2,3,4, 2, 7);
  SS(2043, 1.f, 1.f, 1,2,3,4,5, 3, 0);
  SS(2044, 1.f, 1.f, 2,3,4,5,6, 4, 1);
  SS(2045, 1.f, 1.f, 3,4,5,6,7, 5, 2);
  SS(2046, 1.f, 0.f, 4,5,6,7,0, 6, 3);
  SS(2047, 0.f, 0.f, 5,6,7,0,1, 7, 4);
#undef SS
}

extern "C" void kernel_launch(void* const* d_in, const int* in_sizes, int n_in,
                              void* d_out, int out_size, void* d_ws, size_t ws_size,
                              hipStream_t stream) {
  const float* O  = (const float*)d_in[0];
  const float* Wm = (const float*)d_in[1];
  const float* bm = (const float*)d_in[2];
  const float* Wg = (const float*)d_in[3];
  const float* bg = (const float*)d_in[4];
  float* out = (float*)d_out;

  const size_t NTOT = (size_t)Bq * Tq * Dq;   // 8.39M
  const size_t NWM = 512 * 2560, NWG = 512 * 3072;
  float* Pg = (float*)d_ws;
  float* Gm = Pg + NTOT;
  ushort* WMH = (ushort*)(Gm + NTOT);
  ushort* WML = WMH + NWM;
  ushort* WGH = WML + NWM;
  ushort* WGL = WGH + NWG;
  int* done = (int*)(WGL + NWG);              // 128 ints: band counters

  size_t need = 2 * NTOT * 4 + 2 * (NWM + NWG) * 2 + 128 * 4;  // ~78.5 MB
  if (ws_size >= need) {
    hipMemsetAsync(done, 0, 128 * 4, stream);
    cvt_f16split<<<dim3((NWM / 8 + 255) / 256), dim3(256), 0, stream>>>(Wm, WMH, WML, NWM / 8);
    cvt_f16split<<<dim3((NWG / 8 + 255) / 256), dim3(256), 0, stream>>>(Wg, WGH, WGL, NWG / 8);
    fused_kernel<<<dim3(8 + 16 * 48), dim3(256), 0, stream>>>(
        O, WMH, WML, WGH, WGL, bm, bg, Pg, Gm, out, done);
  } else {
    bool sep = ws_size >= (size_t)(3 * NTOT * 4 + 128 * 4);
    float* Pm = sep ? (Gm + NTOT) : out;
    int* done2 = sep ? (int*)(Pm + NTOT) : (int*)(Gm + NTOT);
    hipMemsetAsync(done2, 6, 128 * 4, stream);  // every byte 6 -> >= 6
    gemm_pre<<<dim3(128, 8), dim3(256), 0, stream>>>(O, Wm, Wg, bm, bg, Pm, Pg, Gm, 0);
    gemm_pre<<<dim3(128, 4), dim3(256), 0, stream>>>(O, Wm, Wg, bm, bg, Pm, Pg, Gm, 1);
    scan_only<<<dim3(Bq), dim3(256), 0, stream>>>(O, Gm, Pg, Pm, out, done2);
  }
}

// Round 20
// 1517.539 us; speedup vs baseline: 1505.6985x; 1.1951x over previous
//
#include <hip/hip_runtime.h>

#define Bq 8
#define Tq 2048
#define Dq 512

typedef __attribute__((ext_vector_type(8))) _Float16 f16x8;  // 8 f16 = 4 VGPRs
typedef __attribute__((ext_vector_type(8))) short u16x8;
typedef __attribute__((ext_vector_type(4))) float f32x4;

// ---------------------------------------------------------------------------
// f32 -> (hi,lo) f16 split planes, x*256 pre-scale (undone by 2^-16 in GEMM).
// Used only for the (small, reused) weight matrices.
// ---------------------------------------------------------------------------
__global__ __launch_bounds__(256) void cvt_f16split(
    const float* __restrict__ s, ushort* __restrict__ hi,
    ushort* __restrict__ lo, int n8) {
  int i = blockIdx.x * 256 + threadIdx.x;
  if (i >= n8) return;
  const float4* sp = reinterpret_cast<const float4*>(s) + i * 2;
  float4 a = sp[0], b = sp[1];
  float x[8] = {a.x, a.y, a.z, a.w, b.x, b.y, b.z, b.w};
  ushort h[8], l[8];
#pragma unroll
  for (int e = 0; e < 8; e++) {
    float xs = x[e] * 256.0f;
    _Float16 hh = (_Float16)xs;
    _Float16 ll = (_Float16)(xs - (float)hh);
    h[e] = *(ushort*)&hh;
    l[e] = *(ushort*)&ll;
  }
  *reinterpret_cast<u16x8*>(hi + (size_t)i * 8) = *reinterpret_cast<u16x8*>(h);
  *reinterpret_cast<u16x8*>(lo + (size_t)i * 8) = *reinterpret_cast<u16x8*>(l);
}

// In-register split of 8 f32 into hi/lo f16 planes — same elementwise math as
// cvt_f16split (R16-verified bit-identical PRE, absmax 0.0078).
__device__ __forceinline__ void split8(const float4& a, const float4& b,
                                       f16x8& hi, f16x8& lo) {
  float x[8] = {a.x, a.y, a.z, a.w, b.x, b.y, b.z, b.w};
#pragma unroll
  for (int e = 0; e < 8; e++) {
    float xs = x[e] * 256.0f;
    _Float16 hh = (_Float16)xs;
    _Float16 ll = (_Float16)(xs - (float)hh);
    hi[e] = hh;
    lo[e] = ll;
  }
}

// ===========================================================================
// Common helpers.
// ===========================================================================
template <int CTRL>
__device__ __forceinline__ float dppadd(float v) {
  int r = __builtin_amdgcn_update_dpp(0, __float_as_int(v), CTRL, 0xF, 0xF, true);
  return v + __int_as_float(r);
}
__device__ __forceinline__ float wave_sum_bcast(float v) {
  v = dppadd<0x111>(v);
  v = dppadd<0x112>(v);
  v = dppadd<0x114>(v);
  v = dppadd<0x118>(v);
  v = dppadd<0x142>(v);
  v = dppadd<0x143>(v);
  return __int_as_float(__builtin_amdgcn_readlane(__float_as_int(v), 63));
}

// Bounded agent-scope wait on a monotone counter (bug -> absmax fail, not hang).
__device__ __forceinline__ void wait_band(int* done, int idx, int target) {
  int it = 0;
  while (__hip_atomic_load(&done[idx], __ATOMIC_ACQUIRE,
                           __HIP_MEMORY_SCOPE_AGENT) < target) {
    __builtin_amdgcn_s_sleep(8);
    if (++it > (1 << 22)) break;
  }
}

// ===========================================================================
// 4-wave cooperative scan step — R15/R16-verified (absmax 0.0078). NUMERICS
// ARE R5's EXACT ORDER (mul-then-fma partials, per-wave scale+mask before
// publish, fma-chain weighted sums). Do not re-derive (R14 lesson: ulp-level
// reordering diverges chaotically, 0.195 fail). R18/R19 lessons: no producer
// throttling (convoy collapse) and no producer pairing (longer tail) — R16's
// free-running unpaired producers are the measured optimum.
// ===========================================================================
template <int S0, int S1, int S2, int S3, int S4, int SLOT, int SLW>
__device__ __forceinline__ void scan_step4(
    int t, float m3, float m4, int lane, int w, int dbase,
    const float* __restrict__ ob, const float* __restrict__ Gb,
    const float* __restrict__ Pgb, const float* __restrict__ pmb,
    float* __restrict__ po, float (*red)[5][4],
    int* done, int bb, int& bandReady,
    float2 (&ow)[8], float2 (&gw)[8], float2 (&pm)[8], float2 (&pg)[8],
    float2& st) {
  int rw = t + 5; if (rw > Tq - 1) rw = Tq - 1;
  int band = rw >> 7;
  if (band > bandReady) {  // once per 128 steps: gate on producer progress
    wait_band(done, bb + band, 12);
    bandReady = band;
  }
  __builtin_amdgcn_sched_barrier(0);
  ow[SLW] = *(const float2*)(ob  + (size_t)rw * Dq + dbase);
  gw[SLW] = *(const float2*)(Gb  + (size_t)rw * Dq + dbase);
  pm[SLW] = *(const float2*)(pmb + (size_t)rw * Dq + dbase);
  pg[SLW] = *(const float2*)(Pgb + (size_t)rw * Dq + dbase);
  __builtin_amdgcn_sched_barrier(0);

  // ---- partial scores over this wave's 128 dims (R5-exact) ----
  const float scale = 0.04419417382415922f;  // 1/sqrt(512)
  float s0 = st.x * ow[S0].x; s0 = fmaf(st.y, ow[S0].y, s0);
  float s1 = st.x * ow[S1].x; s1 = fmaf(st.y, ow[S1].y, s1);
  float s2 = st.x * ow[S2].x; s2 = fmaf(st.y, ow[S2].y, s2);
  float s3 = st.x * ow[S3].x; s3 = fmaf(st.y, ow[S3].y, s3);
  float s4 = st.x * ow[S4].x; s4 = fmaf(st.y, ow[S4].y, s4);
  s0 = wave_sum_bcast(s0);
  s1 = wave_sum_bcast(s1);
  s2 = wave_sum_bcast(s2);
  s3 = wave_sum_bcast(s3);
  s4 = wave_sum_bcast(s4);
  s0 *= scale; s1 *= scale; s2 *= scale;
  s3 *= scale * m3;  // masked scores -> exact 0
  s4 *= scale * m4;

  float pv = s0;
  pv = (lane == 1) ? s1 : pv;
  pv = (lane == 2) ? s2 : pv;
  pv = (lane == 3) ? s3 : pv;
  pv = (lane == 4) ? s4 : pv;
  if (lane < 5) red[t & 1][lane][w] = pv;

  asm volatile("s_waitcnt lgkmcnt(0)" ::: "memory");
  __builtin_amdgcn_sched_barrier(0);
  __builtin_amdgcn_s_barrier();   // raw: no compiler vmcnt(0) drain
  __builtin_amdgcn_sched_barrier(0);

  // ---- full scores + softmax (R5-exact) ----
  float fs[5];
#pragma unroll
  for (int j = 0; j < 5; j++) {
    float4 rv = *(const float4*)(&red[t & 1][j][0]);
    fs[j] = (rv.x + rv.y) + (rv.z + rv.w);
  }
  float mx = fmaxf(fmaxf(fmaxf(fs[0], fs[1]), fmaxf(fs[2], fs[3])), fs[4]);
  float e0 = __expf(fs[0] - mx), e1 = __expf(fs[1] - mx), e2 = __expf(fs[2] - mx);
  float e3 = __expf(fs[3] - mx), e4 = __expf(fs[4] - mx);
  float inv = __fdividef(1.0f, e0 + e1 + e2 + e3 + e4);
  float q0 = e0 * inv, q1 = e1 * inv, q2 = e2 * inv;
  float q3 = e3 * inv * m3, q4 = e4 * inv * m4;  // padded rows contribute 0

  // ---- weighted sums, gate, state update (R5-exact fma chains) ----
  float ax = q0 * ow[S0].x; ax = fmaf(q1, ow[S1].x, ax); ax = fmaf(q2, ow[S2].x, ax);
  ax = fmaf(q3, ow[S3].x, ax); ax = fmaf(q4, ow[S4].x, ax);
  float ay = q0 * ow[S0].y; ay = fmaf(q1, ow[S1].y, ay); ay = fmaf(q2, ow[S2].y, ay);
  ay = fmaf(q3, ow[S3].y, ay); ay = fmaf(q4, ow[S4].y, ay);
  float gx = q0 * gw[S0].x; gx = fmaf(q1, gw[S1].x, gx); gx = fmaf(q2, gw[S2].x, gx);
  gx = fmaf(q3, gw[S3].x, gx); gx = fmaf(q4, gw[S4].x, gx);
  float gy = q0 * gw[S0].y; gy = fmaf(q1, gw[S1].y, gy); gy = fmaf(q2, gw[S2].y, gy);
  gy = fmaf(q3, gw[S3].y, gy); gy = fmaf(q4, gw[S4].y, gy);

  float2 ot;
  ot.x = fmaf(ax, __fdividef(1.f, 1.f + __expf(-(pg[SLOT].x + gx))), pm[SLOT].x);
  ot.y = fmaf(ay, __fdividef(1.f, 1.f + __expf(-(pg[SLOT].y + gy))), pm[SLOT].y);
  st = ot;
  *(float2*)(po + (size_t)t * Dq + dbase) = ot;
}

// ===========================================================================
// FUSED kernel (R16 configuration — measured optimum): blocks 0..7 =
// per-batch 4-wave scans; blocks 8.. = free-running unpaired GEMM producers
// (band-major, done[b*16+band], 12 tiles/band). Producers read f32 O directly
// and split to hi/lo f16 in-register (bit-identical to the cvt pass).
// ===========================================================================
__global__ __launch_bounds__(256, 1) void fused_kernel(
    const float* __restrict__ O,
    const ushort* __restrict__ Wmh, const ushort* __restrict__ Wml,
    const ushort* __restrict__ Wgh, const ushort* __restrict__ Wgl,
    const float* __restrict__ bm, const float* __restrict__ bg,
    float* __restrict__ Pg, float* __restrict__ Gm,
    float* __restrict__ out, int* __restrict__ done) {
  __shared__ __align__(16) float red[2][5][4];  // score partials (scan only)

  if (blockIdx.x < 8) {
    // ---------------- scan: 4 waves, wave w owns dims [128w,128w+128) ------
    int b = blockIdx.x;
    int tid = threadIdx.x;
    int w = tid >> 6;
    int lane = tid & 63;
    int dbase = w * 128 + lane * 2;
    int bb = b * 16;
    const float* ob  = O   + (size_t)b * Tq * Dq;
    const float* Gb  = Gm  + (size_t)b * Tq * Dq;
    const float* Pgb = Pg  + (size_t)b * Tq * Dq;
    const float* pmb = out + (size_t)b * Tq * Dq;  // PRE_mlp lives in d_out
    float* po = out + (size_t)b * Tq * Dq;

    int bandReady = -1;
    wait_band(done, bb + 0, 12);
    bandReady = 0;
    __builtin_amdgcn_sched_barrier(0);

    float2 ow[8], gw[8], pm[8], pg[8];
    float2 st = make_float2(0.f, 0.f);
#pragma unroll
    for (int r = 0; r < 5; r++) {
      ow[r] = *(const float2*)(ob  + (size_t)r * Dq + dbase);
      gw[r] = *(const float2*)(Gb  + (size_t)r * Dq + dbase);
      pm[r] = *(const float2*)(pmb + (size_t)r * Dq + dbase);
      pg[r] = *(const float2*)(Pgb + (size_t)r * Dq + dbase);
    }

#define SS(t_, m3_, m4_, A,B,C,D,E, SL_, LW_)                                  \
    scan_step4<A,B,C,D,E, SL_, LW_>(t_, m3_, m4_, lane, w, dbase, ob, Gb,      \
        Pgb, pmb, po, red, done, bb, bandReady, ow, gw, pm, pg, st)

    SS(0, 0.f, 0.f, 0,1,2,3,4, 0, 5);
    SS(1, 1.f, 0.f, 0,1,2,3,4, 1, 6);
    for (int tb = 2; tb <= 2034; tb += 8) {
      SS(tb+0, 1.f, 1.f, 0,1,2,3,4, 2, 7);
      SS(tb+1, 1.f, 1.f, 1,2,3,4,5, 3, 0);
      SS(tb+2, 1.f, 1.f, 2,3,4,5,6, 4, 1);
      SS(tb+3, 1.f, 1.f, 3,4,5,6,7, 5, 2);
      SS(tb+4, 1.f, 1.f, 4,5,6,7,0, 6, 3);
      SS(tb+5, 1.f, 1.f, 5,6,7,0,1, 7, 4);
      SS(tb+6, 1.f, 1.f, 6,7,0,1,2, 0, 5);
      SS(tb+7, 1.f, 1.f, 7,0,1,2,3, 1, 6);
    }
    SS(2042, 1.f, 1.f, 0,1,2,3,4, 2, 7);
    SS(2043, 1.f, 1.f, 1,2,3,4,5, 3, 0);
    SS(2044, 1.f, 1.f, 2,3,4,5,6, 4, 1);
    SS(2045, 1.f, 1.f, 3,4,5,6,7, 5, 2);
    SS(2046, 1.f, 0.f, 4,5,6,7,0, 6, 3);
    SS(2047, 0.f, 0.f, 5,6,7,0,1, 7, 4);
#undef SS
    return;
  }

  // ---------------- GEMM producer (split-f16, A from f32 O in-register) ----
  int g = blockIdx.x - 8;
  int band = g / 96;
  int rem = g % 96;
  int bat = rem / 12;
  int role = rem % 12;            // 0..7: mode0 by=role; 8..11: mode1 by=role-8
  int bt0 = (bat * 16 + band) * 128;
  int gb = bat * Tq;
  int t0 = bt0 % Tq;

  int tid = threadIdx.x;
  int l = tid & 63, w = tid >> 6;
  int wm = w >> 1, wn = w & 1;
  int r16 = l & 15, kg = l >> 4;

  f32x4 acc[4][4] = {};
  const f16x8 zz = {0, 0, 0, 0, 0, 0, 0, 0};

  if (role >= 8) {
    // ---- MODE 1: G = O @ Wg[:, 2560:]^T ----
    int by = role - 8;
    const ushort *bph[4], *bpl[4];
    int ncol[4];
#pragma unroll
    for (int ni = 0; ni < 4; ni++) {
      int n_g = by * 128 + wn * 64 + ni * 16 + r16;
      ncol[ni] = n_g;
      size_t off = (size_t)n_g * 3072 + 2560 + kg * 8;
      bph[ni] = Wgh + off; bpl[ni] = Wgl + off;
    }
    const float* ap[4];
#pragma unroll
    for (int mi = 0; mi < 4; mi++) {
      ap[mi] = O + (size_t)(bt0 + wm * 64 + mi * 16 + r16) * Dq + kg * 8;
    }
#pragma unroll 4
    for (int ks = 0; ks < 16; ks++) {
      f16x8 Ah[4], Al[4], Bh[4], Bl[4];
#pragma unroll
      for (int mi = 0; mi < 4; mi++) {
        float4 v0 = *(const float4*)ap[mi];
        float4 v1 = *(const float4*)(ap[mi] + 4);
        ap[mi] += 32;
        split8(v0, v1, Ah[mi], Al[mi]);
      }
#pragma unroll
      for (int ni = 0; ni < 4; ni++) {
        Bh[ni] = *(const f16x8*)bph[ni]; bph[ni] += 32;
        Bl[ni] = *(const f16x8*)bpl[ni]; bpl[ni] += 32;
      }
#pragma unroll
      for (int mi = 0; mi < 4; mi++)
#pragma unroll
        for (int ni = 0; ni < 4; ni++) {
          acc[mi][ni] = __builtin_amdgcn_mfma_f32_16x16x32_f16(Ah[mi], Bh[ni], acc[mi][ni], 0, 0, 0);
          acc[mi][ni] = __builtin_amdgcn_mfma_f32_16x16x32_f16(Al[mi], Bh[ni], acc[mi][ni], 0, 0, 0);
          acc[mi][ni] = __builtin_amdgcn_mfma_f32_16x16x32_f16(Ah[mi], Bl[ni], acc[mi][ni], 0, 0, 0);
        }
    }
    const float SC = 1.0f / 65536.0f;
#pragma unroll
    for (int ni = 0; ni < 4; ni++) {
#pragma unroll
      for (int mi = 0; mi < 4; mi++) {
        int rowb = bt0 + wm * 64 + mi * 16 + kg * 4;
#pragma unroll
        for (int rr = 0; rr < 4; rr++)
          Gm[(size_t)(rowb + rr) * Dq + ncol[ni]] = acc[mi][ni][rr] * SC;
      }
    }
  } else {
    // ---- MODE 0: PRE = windowflat @ {Wm | Wg[:, :2560]}^T + bias ----
    int by = role;
    const ushort *bph[4], *bpl[4];
    int ncol[4];
#pragma unroll
    for (int ni = 0; ni < 4; ni++) {
      int n_g = by * 128 + wn * 64 + ni * 16 + r16;
      ncol[ni] = n_g;
      size_t off;
      if (by < 4) { off = (size_t)n_g * 2560 + kg * 8; bph[ni] = Wmh + off; bpl[ni] = Wml + off; }
      else { off = (size_t)(n_g - 512) * 3072 + kg * 8; bph[ni] = Wgh + off; bpl[ni] = Wgl + off; }
    }
    int arow[4][5];
    uint vmask[4];
#pragma unroll
    for (int mi = 0; mi < 4; mi++) {
      int t = t0 + wm * 64 + mi * 16 + r16;
      int sh = 2 - t; if (sh < 0) sh = 0;
      int hi2 = t + 2; if (hi2 > Tq - 1) hi2 = Tq - 1;
      int lo2 = t - 2; if (lo2 < 0) lo2 = 0;
      int nv = hi2 - lo2 + 1;
      uint vm = 0;
#pragma unroll
      for (int j = 0; j < 5; j++) {
        int r = t - 2 + j + sh;
        if (r > Tq - 1) r = Tq - 1;
        arow[mi][j] = gb + r;
        if (j < nv) vm |= (1u << j);
      }
      vmask[mi] = vm;
    }
#pragma unroll
    for (int j = 0; j < 5; j++) {
      const float* ap[4];
      bool v[4];
#pragma unroll
      for (int mi = 0; mi < 4; mi++) {
        ap[mi] = O + (size_t)arow[mi][j] * Dq + kg * 8;
        v[mi] = (vmask[mi] >> j) & 1u;
      }
#pragma unroll 4
      for (int ks = 0; ks < 16; ks++) {
        f16x8 Ah[4], Al[4], Bh[4], Bl[4];
#pragma unroll
        for (int mi = 0; mi < 4; mi++) {
          float4 v0 = *(const float4*)ap[mi];
          float4 v1 = *(const float4*)(ap[mi] + 4);
          ap[mi] += 32;
          f16x8 th, tl;
          split8(v0, v1, th, tl);
          Ah[mi] = v[mi] ? th : zz;
          Al[mi] = v[mi] ? tl : zz;
        }
#pragma unroll
        for (int ni = 0; ni < 4; ni++) {
          Bh[ni] = *(const f16x8*)bph[ni]; bph[ni] += 32;
          Bl[ni] = *(const f16x8*)bpl[ni]; bpl[ni] += 32;
        }
#pragma unroll
        for (int mi = 0; mi < 4; mi++)
#pragma unroll
          for (int ni = 0; ni < 4; ni++) {
            acc[mi][ni] = __builtin_amdgcn_mfma_f32_16x16x32_f16(Ah[mi], Bh[ni], acc[mi][ni], 0, 0, 0);
            acc[mi][ni] = __builtin_amdgcn_mfma_f32_16x16x32_f16(Al[mi], Bh[ni], acc[mi][ni], 0, 0, 0);
            acc[mi][ni] = __builtin_amdgcn_mfma_f32_16x16x32_f16(Ah[mi], Bl[ni], acc[mi][ni], 0, 0, 0);
          }
      }
    }
    const float SC = 1.0f / 65536.0f;
    float* dst = (by < 4) ? out : Pg;  // PRE_mlp -> d_out, PRE_gate -> ws
    const float* bias = (by < 4) ? bm : bg;
#pragma unroll
    for (int ni = 0; ni < 4; ni++) {
      int oc = (by < 4) ? ncol[ni] : ncol[ni] - 512;
      float bi = bias[oc];
#pragma unroll
      for (int mi = 0; mi < 4; mi++) {
        int rowb = bt0 + wm * 64 + mi * 16 + kg * 4;
#pragma unroll
        for (int rr = 0; rr < 4; rr++)
          dst[(size_t)(rowb + rr) * Dq + oc] = fmaf(acc[mi][ni][rr], SC, bi);
      }
    }
  }

  // ---- publish: all stores visible, then bump the band counter ----
  __threadfence();
  __syncthreads();
  if (tid == 0) {
    __hip_atomic_fetch_add(&done[bat * 16 + band], 1, __ATOMIC_RELEASE,
                           __HIP_MEMORY_SCOPE_AGENT);
  }
}

// ---------------------------------------------------------------------------
// f32 fallback (ws too small) — R1-verified serial GEMM + 4-wave scan.
// ---------------------------------------------------------------------------
__global__ __launch_bounds__(256) void gemm_pre(
    const float* __restrict__ O, const float* __restrict__ Wm,
    const float* __restrict__ Wg, const float* __restrict__ bm,
    const float* __restrict__ bg, float* __restrict__ Pm,
    float* __restrict__ Pg, float* __restrict__ Gm, int mode) {
  const int BM = 128, BN = 128, BK = 16;
  __shared__ float As[BK][132];
  __shared__ float Bs[BK][132];
  int tidx = threadIdx.x;
  int bt0 = blockIdx.x * BM;
  int b = bt0 / Tq;
  int t0 = bt0 % Tq;
  int n0 = blockIdx.y * BN;
  int K = mode ? Dq : 5 * Dq;
  int tx = tidx % 16, ty = tidx / 16, lr = tidx >> 2, lc = (tidx & 3) * 4;
  float acc[8][8];
#pragma unroll
  for (int i = 0; i < 8; i++)
#pragma unroll
    for (int j = 0; j < 8; j++) acc[i][j] = 0.f;
  for (int kb = 0; kb < K; kb += BK) {
#pragma unroll
    for (int h = 0; h < 2; h++) {
      int m = lr + h * 64;
      int t = t0 + m;
      float4 av;
      if (mode == 0) {
        int j = kb >> 9;
        int kcol = (kb & 511) + lc;
        int sh = 2 - t; if (sh < 0) sh = 0;
        int r = t - 2 + j + sh;
        int hi = t + 2; if (hi > Tq - 1) hi = Tq - 1;
        int lo2 = t - 2; if (lo2 < 0) lo2 = 0;
        int nv = hi - lo2 + 1;
        if (j < nv) av = *reinterpret_cast<const float4*>(O + ((size_t)b * Tq + r) * Dq + kcol);
        else av = make_float4(0.f, 0.f, 0.f, 0.f);
      } else {
        av = *reinterpret_cast<const float4*>(O + ((size_t)b * Tq + t) * Dq + kb + lc);
      }
      As[lc + 0][m] = av.x; As[lc + 1][m] = av.y;
      As[lc + 2][m] = av.z; As[lc + 3][m] = av.w;
    }
#pragma unroll
    for (int h = 0; h < 2; h++) {
      int n = lr + h * 64;
      int gn = n0 + n;
      const float* wrow;
      int col;
      if (mode == 0) {
        if (gn < 512) { wrow = Wm + (size_t)gn * 2560; col = kb + lc; }
        else          { wrow = Wg + (size_t)(gn - 512) * 3072; col = kb + lc; }
      } else {
        wrow = Wg + (size_t)gn * 3072; col = 2560 + kb + lc;
      }
      float4 bv = *reinterpret_cast<const float4*>(wrow + col);
      Bs[lc + 0][n] = bv.x; Bs[lc + 1][n] = bv.y;
      Bs[lc + 2][n] = bv.z; Bs[lc + 3][n] = bv.w;
    }
    __syncthreads();
#pragma unroll
    for (int kk = 0; kk < BK; kk++) {
      float a[8], bb[8];
      float4 a0 = *reinterpret_cast<float4*>(&As[kk][ty * 8]);
      float4 a1 = *reinterpret_cast<float4*>(&As[kk][ty * 8 + 4]);
      float4 b0 = *reinterpret_cast<float4*>(&Bs[kk][tx * 8]);
      float4 b1 = *reinterpret_cast<float4*>(&Bs[kk][tx * 8 + 4]);
      a[0]=a0.x; a[1]=a0.y; a[2]=a0.z; a[3]=a0.w; a[4]=a1.x; a[5]=a1.y; a[6]=a1.z; a[7]=a1.w;
      bb[0]=b0.x; bb[1]=b0.y; bb[2]=b0.z; bb[3]=b0.w; bb[4]=b1.x; bb[5]=b1.y; bb[6]=b1.z; bb[7]=b1.w;
#pragma unroll
      for (int i = 0; i < 8; i++)
#pragma unroll
        for (int j = 0; j < 8; j++) acc[i][j] = fmaf(a[i], bb[j], acc[i][j]);
    }
    __syncthreads();
  }
  int gn = n0 + tx * 8;
  float bias[8];
  float* dstbase;
  int coloff;
  if (mode == 0) {
    if (gn < 512) {
#pragma unroll
      for (int j = 0; j < 8; j++) bias[j] = bm[gn + j];
      dstbase = Pm; coloff = gn;
    } else {
#pragma unroll
      for (int j = 0; j < 8; j++) bias[j] = bg[gn - 512 + j];
      dstbase = Pg; coloff = gn - 512;
    }
  } else {
#pragma unroll
    for (int j = 0; j < 8; j++) bias[j] = 0.f;
    dstbase = Gm; coloff = gn;
  }
#pragma unroll
  for (int i = 0; i < 8; i++) {
    int bt = bt0 + ty * 8 + i;
    float4 v0 = make_float4(acc[i][0] + bias[0], acc[i][1] + bias[1],
                            acc[i][2] + bias[2], acc[i][3] + bias[3]);
    float4 v1 = make_float4(acc[i][4] + bias[4], acc[i][5] + bias[5],
                            acc[i][6] + bias[6], acc[i][7] + bias[7]);
    float4* d = reinterpret_cast<float4*>(dstbase + (size_t)bt * Dq + coloff);
    d[0] = v0;
    d[1] = v1;
  }
}

// Fallback serial 4-wave scan (done[] pre-filled >= 12 so gates are no-ops).
__global__ __launch_bounds__(256, 1) void scan_only(
    const float* __restrict__ O, const float* __restrict__ Gm,
    const float* __restrict__ Pg, const float* __restrict__ Pm,
    float* __restrict__ out, int* __restrict__ done) {
  __shared__ __align__(16) float red[2][5][4];
  int b = blockIdx.x;
  int tid = threadIdx.x;
  int w = tid >> 6;
  int lane = tid & 63;
  int dbase = w * 128 + lane * 2;
  int bb = b * 16;
  const float* ob  = O  + (size_t)b * Tq * Dq;
  const float* Gb  = Gm + (size_t)b * Tq * Dq;
  const float* Pgb = Pg + (size_t)b * Tq * Dq;
  const float* pmb = Pm + (size_t)b * Tq * Dq;
  float* po = out + (size_t)b * Tq * Dq;
  int bandReady = 15;

  float2 ow[8], gw[8], pm[8], pg[8];
  float2 st = make_float2(0.f, 0.f);
#pragma unroll
  for (int r = 0; r < 5; r++) {
    ow[r] = *(const float2*)(ob  + (size_t)r * Dq + dbase);
    gw[r] = *(const float2*)(Gb  + (size_t)r * Dq + dbase);
    pm[r] = *(const float2*)(pmb + (size_t)r * Dq + dbase);
    pg[r] = *(const float2*)(Pgb + (size_t)r * Dq + dbase);
  }
#define SS(t_, m3_, m4_, A,B,C,D,E, SL_, LW_)                                  \
  scan_step4<A,B,C,D,E, SL_, LW_>(t_, m3_, m4_, lane, w, dbase, ob, Gb,        \
      Pgb, pmb, po, red, done, bb, bandReady, ow, gw, pm, pg, st)
  SS(0, 0.f, 0.f, 0,1,2,3,4, 0, 5);
  SS(1, 1.f, 0.f, 0,1,2,3,4, 1, 6);
  for (int tb = 2; tb <= 2034; tb += 8) {
    SS(tb+0, 1.f, 1.f, 0,1,2,3,4, 2, 7);
    SS(tb+1, 1.f, 1.f, 1,2,3,4,5, 3, 0);
    SS(tb+2, 1.f, 1.f, 2,3,4,5,6, 4, 1);
    SS(tb+3, 1.f, 1.f, 3,4,5,6,7, 5, 2);
    SS(tb+4, 1.f, 1.f, 4,5,6,7,0, 6, 3);
    SS(tb+5, 1.f, 1.f, 5,6,7,0,1, 7, 4);
    SS(tb+6, 1.f, 1.f, 6,7,0,1,2, 0, 5);
    SS(tb+7, 1.f, 1.f, 7,0,1,2,3, 1, 6);
  }
  SS(2042, 1.f, 1.f, 0,1,2,3,4, 2, 7);
  SS(2043, 1.f, 1.f, 1,2,3,4,5, 3, 0);
  SS(2044, 1.f, 1.f, 2,3,4,5,6, 4, 1);
  SS(2045, 1.f, 1.f, 3,4,5,6,7, 5, 2);
  SS(2046, 1.f, 0.f, 4,5,6,7,0, 6, 3);
  SS(2047, 0.f, 0.f, 5,6,7,0,1, 7, 4);
#undef SS
}

extern "C" void kernel_launch(void* const* d_in, const int* in_sizes, int n_in,
                              void* d_out, int out_size, void* d_ws, size_t ws_size,
                              hipStream_t stream) {
  const float* O  = (const float*)d_in[0];
  const float* Wm = (const float*)d_in[1];
  const float* bm = (const float*)d_in[2];
  const float* Wg = (const float*)d_in[3];
  const float* bg = (const float*)d_in[4];
  float* out = (float*)d_out;

  const size_t NTOT = (size_t)Bq * Tq * Dq;   // 8.39M
  const size_t NWM = 512 * 2560, NWG = 512 * 3072;
  float* Pg = (float*)d_ws;
  float* Gm = Pg + NTOT;
  ushort* WMH = (ushort*)(Gm + NTOT);
  ushort* WML = WMH + NWM;
  ushort* WGH = WML + NWM;
  ushort* WGL = WGH + NWG;
  int* done = (int*)(WGL + NWG);              // 128 ints: band counters

  size_t need = 2 * NTOT * 4 + 2 * (NWM + NWG) * 2 + 128 * 4;  // ~78.5 MB
  if (ws_size >= need) {
    hipMemsetAsync(done, 0, 128 * 4, stream);
    cvt_f16split<<<dim3((NWM / 8 + 255) / 256), dim3(256), 0, stream>>>(Wm, WMH, WML, NWM / 8);
    cvt_f16split<<<dim3((NWG / 8 + 255) / 256), dim3(256), 0, stream>>>(Wg, WGH, WGL, NWG / 8);
    fused_kernel<<<dim3(8 + 16 * 96), dim3(256), 0, stream>>>(
        O, WMH, WML, WGH, WGL, bm, bg, Pg, Gm, out, done);
  } else {
    bool sep = ws_size >= (size_t)(3 * NTOT * 4 + 128 * 4);
    float* Pm = sep ? (Gm + NTOT) : out;
    int* done2 = sep ? (int*)(Pm + NTOT) : (int*)(Gm + NTOT);
    hipMemsetAsync(done2, 12, 128 * 4, stream);  // every byte 12 -> >= 12
    gemm_pre<<<dim3(128, 8), dim3(256), 0, stream>>>(O, Wm, Wg, bm, bg, Pm, Pg, Gm, 0);
    gemm_pre<<<dim3(128, 4), dim3(256), 0, stream>>>(O, Wm, Wg, bm, bg, Pm, Pg, Gm, 1);
    scan_only<<<dim3(Bq), dim3(256), 0, stream>>>(O, Gm, Pg, Pm, out, done2);
  }
}